// Round 3
// baseline (1082.795 us; speedup 1.0000x reference)
//
#include <hip/hip_runtime.h>
#include <hip/hip_bf16.h>

// Problem constants (SVGA_7318624272625)
#define N_NODES 50000
#define N_EDGES 800000
#define F_IN    256
#define H_DIM   64

// Layer-1 fused GEMM: outl = x@W1l + b1l, outr = x@W1r.  One wave per row,
// lane = output column (H=64).  x row loaded as float4 broadcast.
__global__ __launch_bounds__(256) void gemm1_k(
    const float* __restrict__ x,
    const float* __restrict__ Wl,
    const float* __restrict__ bl,
    const float* __restrict__ Wr,
    float* __restrict__ outl, float* __restrict__ outr)
{
  int gid  = blockIdx.x * blockDim.x + threadIdx.x;
  int row  = gid >> 6;
  int lane = gid & 63;
  if (row >= N_NODES) return;
  const float4* xrow = (const float4*)(x + (size_t)row * F_IN);
  float accl = 0.f, accr = 0.f;
  for (int kk = 0; kk < F_IN / 4; ++kk) {
    float4 xv = xrow[kk];
    float xs[4] = {xv.x, xv.y, xv.z, xv.w};
#pragma unroll
    for (int j = 0; j < 4; ++j) {
      int k = kk * 4 + j;
      accl += xs[j] * Wl[k * H_DIM + lane];
      accr += xs[j] * Wr[k * H_DIM + lane];
    }
  }
  outl[(size_t)row * H_DIM + lane] = accl + bl[lane];
  outr[(size_t)row * H_DIM + lane] = accr;
}

// Layer-2 fused GEMM (K = H = 64), h is fp32 in workspace.
__global__ __launch_bounds__(256) void gemm2_k(
    const float* __restrict__ h,
    const float* __restrict__ Wl,
    const float* __restrict__ bl,
    const float* __restrict__ Wr,
    float* __restrict__ outl, float* __restrict__ outr)
{
  int gid  = blockIdx.x * blockDim.x + threadIdx.x;
  int row  = gid >> 6;
  int lane = gid & 63;
  if (row >= N_NODES) return;
  const float4* hrow = (const float4*)(h + (size_t)row * H_DIM);
  float accl = 0.f, accr = 0.f;
#pragma unroll
  for (int kk = 0; kk < H_DIM / 4; ++kk) {
    float4 hv = hrow[kk];
    float hs[4] = {hv.x, hv.y, hv.z, hv.w};
#pragma unroll
    for (int j = 0; j < 4; ++j) {
      int k = kk * 4 + j;
      accl += hs[j] * Wl[k * H_DIM + lane];
      accr += hs[j] * Wr[k * H_DIM + lane];
    }
  }
  outl[(size_t)row * H_DIM + lane] = accl + bl[lane];
  outr[(size_t)row * H_DIM + lane] = accr;
}

// Scatter-add messages: one wave per edge, lane = feature dim.
// deg != nullptr -> also count in-degree (layer 1 only; same edges both layers).
__global__ __launch_bounds__(256) void scatter_k(
    const int* __restrict__ ei, const float* __restrict__ m,
    float* __restrict__ agg, float* __restrict__ deg)
{
  long long gid = (long long)blockIdx.x * blockDim.x + threadIdx.x;
  int e    = (int)(gid >> 6);
  int lane = (int)(gid & 63);
  if (e >= N_EDGES) return;
  int s = ei[e];
  int d = ei[N_EDGES + e];
  atomicAdd(&agg[(size_t)d * H_DIM + lane], m[(size_t)s * H_DIM + lane]);
  if (deg != nullptr && lane == 0) atomicAdd(&deg[d], 1.0f);
}

// h = relu(agg/max(deg,1) + xr)
__global__ __launch_bounds__(256) void relu_comb_k(
    const float* __restrict__ agg, const float* __restrict__ deg,
    const float* __restrict__ xr, float* __restrict__ h)
{
  int i = blockIdx.x * blockDim.x + threadIdx.x;
  if (i >= N_NODES * H_DIM) return;
  int row = i >> 6;
  float dv = fmaxf(deg[row], 1.0f);
  float v = agg[i] / dv + xr[i];
  h[i] = fmaxf(v, 0.0f);
}

// z = unitnorm(agg2/max(deg,1) + hr); write fp32 z directly into d_out.
__global__ __launch_bounds__(256) void znorm_k(
    const float* __restrict__ agg, const float* __restrict__ deg,
    const float* __restrict__ hr, float* __restrict__ zout)
{
  int gid  = blockIdx.x * blockDim.x + threadIdx.x;
  int row  = gid >> 6;
  int lane = gid & 63;
  if (row >= N_NODES) return;
  size_t i = (size_t)row * H_DIM + lane;
  float dv = fmaxf(deg[row], 1.0f);
  float v = agg[i] / dv + hr[i];
  float ss = v * v;
#pragma unroll
  for (int m = 32; m >= 1; m >>= 1) ss += __shfl_xor(ss, m, 64);
  zout[i] = v * rsqrtf(fmaxf(ss, 1e-30f));
}

// loss partials: wave per edge (grid-stride), dot over 64 dims by lane,
// softplus(-s); block-reduce then one atomicAdd per block.
__global__ __launch_bounds__(256) void decode_k(
    const int* __restrict__ ei, const float* __restrict__ z,
    float* __restrict__ loss)
{
  int lane = threadIdx.x & 63;
  int wid  = (blockIdx.x * blockDim.x + threadIdx.x) >> 6;
  int nw   = (gridDim.x * blockDim.x) >> 6;
  float part = 0.f;
  for (int e = wid; e < N_EDGES; e += nw) {
    int s = ei[e];
    int d = ei[N_EDGES + e];
    float p = z[(size_t)s * H_DIM + lane] * z[(size_t)d * H_DIM + lane];
#pragma unroll
    for (int m = 32; m >= 1; m >>= 1) p += __shfl_xor(p, m, 64);
    if (lane == 0) part += fmaxf(-p, 0.f) + log1pf(expf(-fabsf(p)));
  }
  __shared__ float sbuf[4];
  int w_in_b = threadIdx.x >> 6;
  if (lane == 0) sbuf[w_in_b] = part;
  __syncthreads();
  if (threadIdx.x == 0) {
    atomicAdd(loss, sbuf[0] + sbuf[1] + sbuf[2] + sbuf[3]);
  }
}

__global__ void fin_k(const float* __restrict__ loss, float* __restrict__ out)
{
  out[(size_t)N_NODES * H_DIM] = loss[0] / (float)N_EDGES;
}

extern "C" void kernel_launch(void* const* d_in, const int* in_sizes, int n_in,
                              void* d_out, int out_size, void* d_ws, size_t ws_size,
                              hipStream_t stream)
{
  (void)in_sizes; (void)n_in; (void)out_size; (void)ws_size;
  const float* x   = (const float*)d_in[0];
  const int*   ei  = (const int*)d_in[1];
  const float* W1l = (const float*)d_in[2];
  const float* b1l = (const float*)d_in[3];
  const float* W1r = (const float*)d_in[4];
  const float* W2l = (const float*)d_in[5];
  const float* b2l = (const float*)d_in[6];
  const float* W2r = (const float*)d_in[7];
  float* out = (float*)d_out;  // fp32 output: z [N*H] ++ loss [1]

  // Workspace layout (fp32): P,Q,R are N*H each, then deg[N], loss[1].
  float* P    = (float*)d_ws;
  float* Q    = P + (size_t)N_NODES * H_DIM;
  float* R    = Q + (size_t)N_NODES * H_DIM;
  float* deg  = R + (size_t)N_NODES * H_DIM;
  float* loss = deg + N_NODES;

  hipMemsetAsync(R,    0, sizeof(float) * (size_t)N_NODES * H_DIM, stream);
  hipMemsetAsync(deg,  0, sizeof(float) * N_NODES, stream);
  hipMemsetAsync(loss, 0, sizeof(float), stream);

  dim3 blk(256);
  dim3 g_rows((N_NODES * 64 + 255) / 256);                    // one wave per row
  dim3 g_edges((unsigned)(((size_t)N_EDGES * 64 + 255) / 256));
  dim3 g_elem((N_NODES * H_DIM + 255) / 256);

  // Layer 1: P=m1, Q=xr
  gemm1_k<<<g_rows, blk, 0, stream>>>(x, W1l, b1l, W1r, P, Q);
  // agg1 -> R, deg
  scatter_k<<<g_edges, blk, 0, stream>>>(ei, P, R, deg);
  // h = relu(R/deg + Q) -> P
  relu_comb_k<<<g_elem, blk, 0, stream>>>(R, deg, Q, P);
  // Layer 2: m2 -> Q, hr -> R
  gemm2_k<<<g_rows, blk, 0, stream>>>(P, W2l, b2l, W2r, Q, R);
  // agg2 -> P (zero first)
  hipMemsetAsync(P, 0, sizeof(float) * (size_t)N_NODES * H_DIM, stream);
  scatter_k<<<g_edges, blk, 0, stream>>>(ei, Q, P, nullptr);
  // z = norm(P/deg + R) -> out (fp32)
  znorm_k<<<g_rows, blk, 0, stream>>>(P, deg, R, out);
  // loss
  decode_k<<<dim3(1024), blk, 0, stream>>>(ei, out, loss);
  fin_k<<<dim3(1), dim3(1), 0, stream>>>(loss, out);
}

// Round 4
// 848.346 us; speedup vs baseline: 1.2764x; 1.2764x over previous
//
#include <hip/hip_runtime.h>

// Problem constants (SVGA_7318624272625)
#define N_NODES 50000
#define N_EDGES 800000
#define F_IN    256
#define H_DIM   64

// Tiled dual-GEMM: outl = X@Wl + bl, outr = X@Wr.  X:[N,K], W:[K,64].
// Block = 256 thr = 4 waves; block tiles 32 rows (LDS-staged), each wave
// computes 8 rows x 64 cols for BOTH W's -> 16 FMA per W-load pair
// (vs 2 in the naive version: was latency-bound at VALUBusy=10%).
template<int K>
__global__ __launch_bounds__(256) void gemm_tile_k(
    const float* __restrict__ X,
    const float* __restrict__ Wl,
    const float* __restrict__ bl,
    const float* __restrict__ Wr,
    float* __restrict__ outl, float* __restrict__ outr)
{
  __shared__ float xs[32][K];           // K=256: 32 KB, K=64: 8 KB
  const int row0 = blockIdx.x * 32;
  const int nvec   = 32 * K / 4;
  const int totvec = N_NODES * K / 4;
  const float4* Xv = (const float4*)X;
  float4* xsv = (float4*)&xs[0][0];
  const int base = row0 * (K / 4);
  for (int i = threadIdx.x; i < nvec; i += 256) {
    int gi = base + i;
    xsv[i] = (gi < totvec) ? Xv[gi] : make_float4(0.f, 0.f, 0.f, 0.f);
  }
  __syncthreads();
  const int lane = threadIdx.x & 63;
  const int r0   = (threadIdx.x >> 6) * 8;
  float accl[8], accr[8];
#pragma unroll
  for (int r = 0; r < 8; ++r) { accl[r] = 0.f; accr[r] = 0.f; }
  for (int k4 = 0; k4 < K; k4 += 4) {
    float4 xv[8];
#pragma unroll
    for (int r = 0; r < 8; ++r) xv[r] = *(const float4*)&xs[r0 + r][k4];  // broadcast, conflict-free
#pragma unroll
    for (int j = 0; j < 4; ++j) {
      float wl = Wl[(k4 + j) * H_DIM + lane];
      float wr = Wr[(k4 + j) * H_DIM + lane];
#pragma unroll
      for (int r = 0; r < 8; ++r) {
        float xx = (j == 0) ? xv[r].x : (j == 1) ? xv[r].y : (j == 2) ? xv[r].z : xv[r].w;
        accl[r] = fmaf(xx, wl, accl[r]);
        accr[r] = fmaf(xx, wr, accr[r]);
      }
    }
  }
  float bias = bl[lane];
#pragma unroll
  for (int r = 0; r < 8; ++r) {
    int row = row0 + r0 + r;
    if (row < N_NODES) {
      outl[(size_t)row * H_DIM + lane] = accl[r] + bias;
      outr[(size_t)row * H_DIM + lane] = accr[r];
    }
  }
}

// ---- CSR build (replaces 102M fp32 atomics with 1.6M int atomics) ----
__global__ __launch_bounds__(256) void hist_k(const int* __restrict__ ei,
                                              int* __restrict__ cnt)
{
  int e = blockIdx.x * 256 + threadIdx.x;
  if (e >= N_EDGES) return;
  atomicAdd(&cnt[ei[N_EDGES + e]], 1);
}

// Exclusive scan of cnt[50000] -> rowptr[50001] (+ cursor copy), one block.
__global__ __launch_bounds__(1024) void scan_k(const int* __restrict__ cnt,
                                               int* __restrict__ rowptr,
                                               int* __restrict__ cursor)
{
  __shared__ int part[1024];
  const int t = threadIdx.x;
  const int CHUNK = (N_NODES + 1023) / 1024;   // 49
  const int base = t * CHUNK;
  int s = 0;
  for (int i = 0; i < CHUNK; ++i) {
    int idx = base + i;
    if (idx < N_NODES) s += cnt[idx];
  }
  part[t] = s;
  __syncthreads();
  for (int off = 1; off < 1024; off <<= 1) {   // Hillis-Steele inclusive
    int v = (t >= off) ? part[t - off] : 0;
    __syncthreads();
    part[t] += v;
    __syncthreads();
  }
  int run = (t == 0) ? 0 : part[t - 1];
  for (int i = 0; i < CHUNK; ++i) {
    int idx = base + i;
    if (idx < N_NODES) {
      rowptr[idx] = run;
      cursor[idx] = run;
      run += cnt[idx];
    }
  }
  if (t == 1023) rowptr[N_NODES] = part[1023];
}

__global__ __launch_bounds__(256) void fill_k(const int* __restrict__ ei,
                                              int* __restrict__ cursor,
                                              int* __restrict__ esrc)
{
  int e = blockIdx.x * 256 + threadIdx.x;
  if (e >= N_EDGES) return;
  int s = ei[e], d = ei[N_EDGES + e];
  int pos = atomicAdd(&cursor[d], 1);
  esrc[pos] = s;
}

// ---- Fused aggregation: wave per dst node, lane = feature ----
// h = relu(mean_{s in row} m[s] + xr)
__global__ __launch_bounds__(256) void agg1_k(
    const int* __restrict__ rowptr, const int* __restrict__ esrc,
    const float* __restrict__ m, const float* __restrict__ xr,
    float* __restrict__ h)
{
  int gid = blockIdx.x * 256 + threadIdx.x;
  int row = gid >> 6, lane = gid & 63;
  if (row >= N_NODES) return;
  int b = rowptr[row], e = rowptr[row + 1];
  float acc = 0.f;
  for (int i = b; i < e; ++i)
    acc += m[(size_t)esrc[i] * H_DIM + lane];
  float dv = fmaxf((float)(e - b), 1.f);
  size_t o = (size_t)row * H_DIM + lane;
  h[o] = fmaxf(acc / dv + xr[o], 0.f);
}

// z = unitnorm(mean m2 + hr), straight into d_out
__global__ __launch_bounds__(256) void agg2_k(
    const int* __restrict__ rowptr, const int* __restrict__ esrc,
    const float* __restrict__ m, const float* __restrict__ hr,
    float* __restrict__ zout)
{
  int gid = blockIdx.x * 256 + threadIdx.x;
  int row = gid >> 6, lane = gid & 63;
  if (row >= N_NODES) return;
  int b = rowptr[row], e = rowptr[row + 1];
  float acc = 0.f;
  for (int i = b; i < e; ++i)
    acc += m[(size_t)esrc[i] * H_DIM + lane];
  float dv = fmaxf((float)(e - b), 1.f);
  size_t o = (size_t)row * H_DIM + lane;
  float v = acc / dv + hr[o];
  float ss = v * v;
#pragma unroll
  for (int mm = 32; mm >= 1; mm >>= 1) ss += __shfl_xor(ss, mm, 64);
  zout[o] = v * rsqrtf(fmaxf(ss, 1e-30f));
}

// loss partials: wave per edge (grid-stride), dot over 64 dims by lane.
__global__ __launch_bounds__(256) void decode_k(
    const int* __restrict__ ei, const float* __restrict__ z,
    float* __restrict__ loss)
{
  int lane = threadIdx.x & 63;
  int wid  = (blockIdx.x * blockDim.x + threadIdx.x) >> 6;
  int nw   = (gridDim.x * blockDim.x) >> 6;
  float part = 0.f;
  for (int e = wid; e < N_EDGES; e += nw) {
    int s = ei[e];
    int d = ei[N_EDGES + e];
    float p = z[(size_t)s * H_DIM + lane] * z[(size_t)d * H_DIM + lane];
#pragma unroll
    for (int m = 32; m >= 1; m >>= 1) p += __shfl_xor(p, m, 64);
    if (lane == 0) part += fmaxf(-p, 0.f) + log1pf(expf(-fabsf(p)));
  }
  __shared__ float sbuf[4];
  int w_in_b = threadIdx.x >> 6;
  if (lane == 0) sbuf[w_in_b] = part;
  __syncthreads();
  if (threadIdx.x == 0)
    atomicAdd(loss, sbuf[0] + sbuf[1] + sbuf[2] + sbuf[3]);
}

__global__ void fin_k(const float* __restrict__ loss, float* __restrict__ out)
{
  out[(size_t)N_NODES * H_DIM] = loss[0] / (float)N_EDGES;
}

extern "C" void kernel_launch(void* const* d_in, const int* in_sizes, int n_in,
                              void* d_out, int out_size, void* d_ws, size_t ws_size,
                              hipStream_t stream)
{
  (void)in_sizes; (void)n_in; (void)out_size; (void)ws_size;
  const float* x   = (const float*)d_in[0];
  const int*   ei  = (const int*)d_in[1];
  const float* W1l = (const float*)d_in[2];
  const float* b1l = (const float*)d_in[3];
  const float* W1r = (const float*)d_in[4];
  const float* W2l = (const float*)d_in[5];
  const float* b2l = (const float*)d_in[6];
  const float* W2r = (const float*)d_in[7];
  float* out = (float*)d_out;  // fp32: z [N*H] ++ loss [1]

  const size_t NH = (size_t)N_NODES * H_DIM;
  float* P      = (float*)d_ws;          // m1 -> m2
  float* Q      = P + NH;                // xr -> hr
  float* R      = Q + NH;                // h
  float* loss   = R + NH;
  int*   cnt    = (int*)(loss + 1);
  int*   rowptr = cnt + N_NODES;         // N+1
  int*   cursor = rowptr + N_NODES + 1;
  int*   esrc   = cursor + N_NODES;      // E

  hipMemsetAsync(cnt,  0, sizeof(int) * N_NODES, stream);
  hipMemsetAsync(loss, 0, sizeof(float), stream);

  dim3 blk(256);
  dim3 g_tile((N_NODES + 31) / 32);
  dim3 g_edge((N_EDGES + 255) / 256);
  dim3 g_node((N_NODES * 64 + 255) / 256);

  // CSR build
  hist_k<<<g_edge, blk, 0, stream>>>(ei, cnt);
  scan_k<<<dim3(1), dim3(1024), 0, stream>>>(cnt, rowptr, cursor);
  fill_k<<<g_edge, blk, 0, stream>>>(ei, cursor, esrc);
  // Layer 1
  gemm_tile_k<F_IN><<<g_tile, blk, 0, stream>>>(x, W1l, b1l, W1r, P, Q);
  agg1_k<<<g_node, blk, 0, stream>>>(rowptr, esrc, P, Q, R);
  // Layer 2
  gemm_tile_k<H_DIM><<<g_tile, blk, 0, stream>>>(R, W2l, b2l, W2r, P, Q);
  agg2_k<<<g_node, blk, 0, stream>>>(rowptr, esrc, P, Q, out);
  // Decode + loss
  decode_k<<<dim3(2048), blk, 0, stream>>>(ei, out, loss);
  fin_k<<<dim3(1), dim3(1), 0, stream>>>(loss, out);
}

// Round 5
// 653.125 us; speedup vs baseline: 1.6579x; 1.2989x over previous
//
#include <hip/hip_runtime.h>

// Problem constants (SVGA_7318624272625)
#define N_NODES 50000
#define N_EDGES 800000
#define F_IN    256
#define H_DIM   64

// Tiled dual-GEMM: outl = X@Wl + bl, outr = X@Wr.  X:[N,K], W:[K,64].
// Block = 256 thr = 4 waves; block tiles 32 rows (LDS-staged), each wave
// computes 8 rows x 64 cols for BOTH W's -> 16 FMA per W-load pair.
template<int K>
__global__ __launch_bounds__(256) void gemm_tile_k(
    const float* __restrict__ X,
    const float* __restrict__ Wl,
    const float* __restrict__ bl,
    const float* __restrict__ Wr,
    float* __restrict__ outl, float* __restrict__ outr)
{
  __shared__ float xs[32][K];           // K=256: 32 KB, K=64: 8 KB
  const int row0 = blockIdx.x * 32;
  const int nvec   = 32 * K / 4;
  const int totvec = N_NODES * K / 4;
  const float4* Xv = (const float4*)X;
  float4* xsv = (float4*)&xs[0][0];
  const int base = row0 * (K / 4);
  for (int i = threadIdx.x; i < nvec; i += 256) {
    int gi = base + i;
    xsv[i] = (gi < totvec) ? Xv[gi] : make_float4(0.f, 0.f, 0.f, 0.f);
  }
  __syncthreads();
  const int lane = threadIdx.x & 63;
  const int r0   = (threadIdx.x >> 6) * 8;
  float accl[8], accr[8];
#pragma unroll
  for (int r = 0; r < 8; ++r) { accl[r] = 0.f; accr[r] = 0.f; }
  for (int k4 = 0; k4 < K; k4 += 4) {
    float4 xv[8];
#pragma unroll
    for (int r = 0; r < 8; ++r) xv[r] = *(const float4*)&xs[r0 + r][k4];  // broadcast
#pragma unroll
    for (int j = 0; j < 4; ++j) {
      float wl = Wl[(k4 + j) * H_DIM + lane];
      float wr = Wr[(k4 + j) * H_DIM + lane];
#pragma unroll
      for (int r = 0; r < 8; ++r) {
        float xx = (j == 0) ? xv[r].x : (j == 1) ? xv[r].y : (j == 2) ? xv[r].z : xv[r].w;
        accl[r] = fmaf(xx, wl, accl[r]);
        accr[r] = fmaf(xx, wr, accr[r]);
      }
    }
  }
  float bias = bl[lane];
#pragma unroll
  for (int r = 0; r < 8; ++r) {
    int row = row0 + r0 + r;
    if (row < N_NODES) {
      outl[(size_t)row * H_DIM + lane] = accl[r] + bias;
      outr[(size_t)row * H_DIM + lane] = accr[r];
    }
  }
}

// ---- CSR build ----
__global__ __launch_bounds__(256) void hist_k(const int* __restrict__ ei,
                                              int* __restrict__ cnt)
{
  int e = blockIdx.x * 256 + threadIdx.x;
  if (e >= N_EDGES) return;
  atomicAdd(&cnt[ei[N_EDGES + e]], 1);
}

// Exclusive scan of cnt[50000] -> rowptr[50001] (+ cursor copy), one block.
__global__ __launch_bounds__(1024) void scan_k(const int* __restrict__ cnt,
                                               int* __restrict__ rowptr,
                                               int* __restrict__ cursor)
{
  __shared__ int part[1024];
  const int t = threadIdx.x;
  const int CHUNK = (N_NODES + 1023) / 1024;   // 49
  const int base = t * CHUNK;
  int s = 0;
  for (int i = 0; i < CHUNK; ++i) {
    int idx = base + i;
    if (idx < N_NODES) s += cnt[idx];
  }
  part[t] = s;
  __syncthreads();
  for (int off = 1; off < 1024; off <<= 1) {   // Hillis-Steele inclusive
    int v = (t >= off) ? part[t - off] : 0;
    __syncthreads();
    part[t] += v;
    __syncthreads();
  }
  int run = (t == 0) ? 0 : part[t - 1];
  for (int i = 0; i < CHUNK; ++i) {
    int idx = base + i;
    if (idx < N_NODES) {
      rowptr[idx] = run;
      cursor[idx] = run;
      run += cnt[idx];
    }
  }
  if (t == 1023) rowptr[N_NODES] = part[1023];
}

__global__ __launch_bounds__(256) void fill_k(const int* __restrict__ ei,
                                              int* __restrict__ cursor,
                                              int* __restrict__ esrc)
{
  int e = blockIdx.x * 256 + threadIdx.x;
  if (e >= N_EDGES) return;
  int s = ei[e], d = ei[N_EDGES + e];
  int pos = atomicAdd(&cursor[d], 1);
  esrc[pos] = s;
}

// ---- Fused aggregation: wave per dst node, lane = feature ----
// 4-way unrolled neighbor loop: 4 independent index loads + 4 parallel
// row gathers per iteration (4-deep memory-level parallelism).
__device__ __forceinline__ float agg_row(const int* __restrict__ esrc,
                                         const float* __restrict__ m,
                                         int b, int e, int lane)
{
  float a0 = 0.f, a1 = 0.f, a2 = 0.f, a3 = 0.f;
  int i = b;
  for (; i + 4 <= e; i += 4) {
    int s0 = esrc[i], s1 = esrc[i + 1], s2 = esrc[i + 2], s3 = esrc[i + 3];
    a0 += m[(size_t)s0 * H_DIM + lane];
    a1 += m[(size_t)s1 * H_DIM + lane];
    a2 += m[(size_t)s2 * H_DIM + lane];
    a3 += m[(size_t)s3 * H_DIM + lane];
  }
  for (; i < e; ++i) a0 += m[(size_t)esrc[i] * H_DIM + lane];
  return (a0 + a1) + (a2 + a3);
}

// h = relu(mean_{s in row} m[s] + xr)
__global__ __launch_bounds__(256) void agg1_k(
    const int* __restrict__ rowptr, const int* __restrict__ esrc,
    const float* __restrict__ m, const float* __restrict__ xr,
    float* __restrict__ h)
{
  int gid = blockIdx.x * 256 + threadIdx.x;
  int row = gid >> 6, lane = gid & 63;
  if (row >= N_NODES) return;
  int b = rowptr[row], e = rowptr[row + 1];
  float acc = agg_row(esrc, m, b, e, lane);
  float dv = fmaxf((float)(e - b), 1.f);
  size_t o = (size_t)row * H_DIM + lane;
  h[o] = fmaxf(acc / dv + xr[o], 0.f);
}

// z = unitnorm(mean m2 + hr), straight into d_out
__global__ __launch_bounds__(256) void agg2_k(
    const int* __restrict__ rowptr, const int* __restrict__ esrc,
    const float* __restrict__ m, const float* __restrict__ hr,
    float* __restrict__ zout)
{
  int gid = blockIdx.x * 256 + threadIdx.x;
  int row = gid >> 6, lane = gid & 63;
  if (row >= N_NODES) return;
  int b = rowptr[row], e = rowptr[row + 1];
  float acc = agg_row(esrc, m, b, e, lane);
  float dv = fmaxf((float)(e - b), 1.f);
  size_t o = (size_t)row * H_DIM + lane;
  float v = acc / dv + hr[o];
  float ss = v * v;
#pragma unroll
  for (int mm = 32; mm >= 1; mm >>= 1) ss += __shfl_xor(ss, mm, 64);
  zout[o] = v * rsqrtf(fmaxf(ss, 1e-30f));
}

// Decode: ONE THREAD PER EDGE (was wave-per-edge at VALUBusy=93%).
// Each thread: 2 x 256B contiguous row reads (L1-friendly), 64 FMA, softplus
// on every lane. 800000 = 3125 * 256 exactly.
__global__ __launch_bounds__(256) void decode_k(
    const int* __restrict__ ei, const float* __restrict__ z,
    float* __restrict__ loss)
{
  int e = blockIdx.x * 256 + threadIdx.x;
  float part = 0.f;
  if (e < N_EDGES) {
    int s = ei[e];
    int d = ei[N_EDGES + e];
    const float4* zs = (const float4*)(z + (size_t)s * H_DIM);
    const float4* zd = (const float4*)(z + (size_t)d * H_DIM);
    float p = 0.f;
#pragma unroll
    for (int k = 0; k < 16; ++k) {
      float4 a = zs[k], b = zd[k];
      p = fmaf(a.x, b.x, p); p = fmaf(a.y, b.y, p);
      p = fmaf(a.z, b.z, p); p = fmaf(a.w, b.w, p);
    }
    part = fmaxf(-p, 0.f) + log1pf(expf(-fabsf(p)));
  }
  // wave reduce then block reduce
#pragma unroll
  for (int m = 32; m >= 1; m >>= 1) part += __shfl_xor(part, m, 64);
  __shared__ float sbuf[4];
  int lane = threadIdx.x & 63, w = threadIdx.x >> 6;
  if (lane == 0) sbuf[w] = part;
  __syncthreads();
  if (threadIdx.x == 0)
    atomicAdd(loss, sbuf[0] + sbuf[1] + sbuf[2] + sbuf[3]);
}

__global__ void fin_k(const float* __restrict__ loss, float* __restrict__ out)
{
  out[(size_t)N_NODES * H_DIM] = loss[0] / (float)N_EDGES;
}

extern "C" void kernel_launch(void* const* d_in, const int* in_sizes, int n_in,
                              void* d_out, int out_size, void* d_ws, size_t ws_size,
                              hipStream_t stream)
{
  (void)in_sizes; (void)n_in; (void)out_size; (void)ws_size;
  const float* x   = (const float*)d_in[0];
  const int*   ei  = (const int*)d_in[1];
  const float* W1l = (const float*)d_in[2];
  const float* b1l = (const float*)d_in[3];
  const float* W1r = (const float*)d_in[4];
  const float* W2l = (const float*)d_in[5];
  const float* b2l = (const float*)d_in[6];
  const float* W2r = (const float*)d_in[7];
  float* out = (float*)d_out;  // fp32: z [N*H] ++ loss [1]

  const size_t NH = (size_t)N_NODES * H_DIM;
  float* P      = (float*)d_ws;          // m1 -> m2
  float* Q      = P + NH;                // xr -> hr
  float* R      = Q + NH;                // h
  float* loss   = R + NH;
  int*   cnt    = (int*)(loss + 1);
  int*   rowptr = cnt + N_NODES;         // N+1
  int*   cursor = rowptr + N_NODES + 1;
  int*   esrc   = cursor + N_NODES;      // E

  hipMemsetAsync(cnt,  0, sizeof(int) * N_NODES, stream);
  hipMemsetAsync(loss, 0, sizeof(float), stream);

  dim3 blk(256);
  dim3 g_tile((N_NODES + 31) / 32);
  dim3 g_edge((N_EDGES + 255) / 256);
  dim3 g_node((N_NODES * 64 + 255) / 256);

  // CSR build
  hist_k<<<g_edge, blk, 0, stream>>>(ei, cnt);
  scan_k<<<dim3(1), dim3(1024), 0, stream>>>(cnt, rowptr, cursor);
  fill_k<<<g_edge, blk, 0, stream>>>(ei, cursor, esrc);
  // Layer 1
  gemm_tile_k<F_IN><<<g_tile, blk, 0, stream>>>(x, W1l, b1l, W1r, P, Q);
  agg1_k<<<g_node, blk, 0, stream>>>(rowptr, esrc, P, Q, R);
  // Layer 2
  gemm_tile_k<H_DIM><<<g_tile, blk, 0, stream>>>(R, W2l, b2l, W2r, P, Q);
  agg2_k<<<g_node, blk, 0, stream>>>(rowptr, esrc, P, Q, out);
  // Decode + loss
  decode_k<<<g_edge, blk, 0, stream>>>(ei, out, loss);
  fin_k<<<dim3(1), dim3(1), 0, stream>>>(loss, out);
}

// Round 6
// 557.027 us; speedup vs baseline: 1.9439x; 1.1725x over previous
//
#include <hip/hip_runtime.h>

// Problem constants (SVGA_7318624272625)
#define N_NODES 50000
#define N_EDGES 800000
#define F_IN    256
#define H_DIM   64

// Tiled dual-GEMM: outl = X@Wl + bl, outr = X@Wr.  X:[N,K], W:[K,64].
// Block = 256 thr = 4 waves; block tiles 32 rows (LDS-staged), each wave
// computes 8 rows x 64 cols for BOTH W's -> 16 FMA per W-load pair.
// R5 lesson: K=64 full unroll spilled (VGPR=256, 234MB scratch writes).
// unroll 2 + launch_bounds(256,4) caps VGPR at 128.
template<int K>
__global__ __launch_bounds__(256, 4) void gemm_tile_k(
    const float* __restrict__ X,
    const float* __restrict__ Wl,
    const float* __restrict__ bl,
    const float* __restrict__ Wr,
    float* __restrict__ outl, float* __restrict__ outr)
{
  __shared__ float xs[32][K];           // K=256: 32 KB, K=64: 8 KB
  const int row0 = blockIdx.x * 32;
  const int nvec   = 32 * K / 4;
  const int totvec = N_NODES * K / 4;
  const float4* Xv = (const float4*)X;
  float4* xsv = (float4*)&xs[0][0];
  const int base = row0 * (K / 4);
  for (int i = threadIdx.x; i < nvec; i += 256) {
    int gi = base + i;
    xsv[i] = (gi < totvec) ? Xv[gi] : make_float4(0.f, 0.f, 0.f, 0.f);
  }
  __syncthreads();
  const int lane = threadIdx.x & 63;
  const int r0   = (threadIdx.x >> 6) * 8;
  float accl[8], accr[8];
#pragma unroll
  for (int r = 0; r < 8; ++r) { accl[r] = 0.f; accr[r] = 0.f; }
#pragma unroll 2
  for (int k4 = 0; k4 < K; k4 += 4) {
    float4 xv[8];
#pragma unroll
    for (int r = 0; r < 8; ++r) xv[r] = *(const float4*)&xs[r0 + r][k4];  // broadcast
#pragma unroll
    for (int j = 0; j < 4; ++j) {
      float wl = Wl[(k4 + j) * H_DIM + lane];
      float wr = Wr[(k4 + j) * H_DIM + lane];
#pragma unroll
      for (int r = 0; r < 8; ++r) {
        float xx = (j == 0) ? xv[r].x : (j == 1) ? xv[r].y : (j == 2) ? xv[r].z : xv[r].w;
        accl[r] = fmaf(xx, wl, accl[r]);
        accr[r] = fmaf(xx, wr, accr[r]);
      }
    }
  }
  float bias = bl[lane];
#pragma unroll
  for (int r = 0; r < 8; ++r) {
    int row = row0 + r0 + r;
    if (row < N_NODES) {
      outl[(size_t)row * H_DIM + lane] = accl[r] + bias;
      outr[(size_t)row * H_DIM + lane] = accr[r];
    }
  }
}

// ---- CSR build ----
__global__ __launch_bounds__(256) void hist_k(const int* __restrict__ ei,
                                              int* __restrict__ cnt)
{
  int e = blockIdx.x * 256 + threadIdx.x;
  if (e >= N_EDGES) return;
  atomicAdd(&cnt[ei[N_EDGES + e]], 1);
}

// Exclusive scan of cnt[50000] -> rowptr[50001] (+ cursor copy), one block.
__global__ __launch_bounds__(1024) void scan_k(const int* __restrict__ cnt,
                                               int* __restrict__ rowptr,
                                               int* __restrict__ cursor)
{
  __shared__ int part[1024];
  const int t = threadIdx.x;
  const int CHUNK = (N_NODES + 1023) / 1024;   // 49
  const int base = t * CHUNK;
  int s = 0;
  for (int i = 0; i < CHUNK; ++i) {
    int idx = base + i;
    if (idx < N_NODES) s += cnt[idx];
  }
  part[t] = s;
  __syncthreads();
  for (int off = 1; off < 1024; off <<= 1) {   // Hillis-Steele inclusive
    int v = (t >= off) ? part[t - off] : 0;
    __syncthreads();
    part[t] += v;
    __syncthreads();
  }
  int run = (t == 0) ? 0 : part[t - 1];
  for (int i = 0; i < CHUNK; ++i) {
    int idx = base + i;
    if (idx < N_NODES) {
      rowptr[idx] = run;
      cursor[idx] = run;
      run += cnt[idx];
    }
  }
  if (t == 1023) rowptr[N_NODES] = part[1023];
}

__global__ __launch_bounds__(256) void fill_k(const int* __restrict__ ei,
                                              int* __restrict__ cursor,
                                              int* __restrict__ esrc)
{
  int e = blockIdx.x * 256 + threadIdx.x;
  if (e >= N_EDGES) return;
  int s = ei[e], d = ei[N_EDGES + e];
  int pos = atomicAdd(&cursor[d], 1);
  esrc[pos] = s;
}

// ---- Fused aggregation: wave per dst node, lane = feature ----
// 4-way unrolled neighbor loop: 4 independent index loads + 4 parallel
// row gathers per iteration (4-deep memory-level parallelism).
__device__ __forceinline__ float agg_row(const int* __restrict__ esrc,
                                         const float* __restrict__ m,
                                         int b, int e, int lane)
{
  float a0 = 0.f, a1 = 0.f, a2 = 0.f, a3 = 0.f;
  int i = b;
  for (; i + 4 <= e; i += 4) {
    int s0 = esrc[i], s1 = esrc[i + 1], s2 = esrc[i + 2], s3 = esrc[i + 3];
    a0 += m[(size_t)s0 * H_DIM + lane];
    a1 += m[(size_t)s1 * H_DIM + lane];
    a2 += m[(size_t)s2 * H_DIM + lane];
    a3 += m[(size_t)s3 * H_DIM + lane];
  }
  for (; i < e; ++i) a0 += m[(size_t)esrc[i] * H_DIM + lane];
  return (a0 + a1) + (a2 + a3);
}

// h = relu(mean_{s in row} m[s] + xr)
__global__ __launch_bounds__(256) void agg1_k(
    const int* __restrict__ rowptr, const int* __restrict__ esrc,
    const float* __restrict__ m, const float* __restrict__ xr,
    float* __restrict__ h)
{
  int gid = blockIdx.x * 256 + threadIdx.x;
  int row = gid >> 6, lane = gid & 63;
  if (row >= N_NODES) return;
  int b = rowptr[row], e = rowptr[row + 1];
  float acc = agg_row(esrc, m, b, e, lane);
  float dv = fmaxf((float)(e - b), 1.f);
  size_t o = (size_t)row * H_DIM + lane;
  h[o] = fmaxf(acc / dv + xr[o], 0.f);
}

// z = unitnorm(mean m2 + hr), straight into d_out
__global__ __launch_bounds__(256) void agg2_k(
    const int* __restrict__ rowptr, const int* __restrict__ esrc,
    const float* __restrict__ m, const float* __restrict__ hr,
    float* __restrict__ zout)
{
  int gid = blockIdx.x * 256 + threadIdx.x;
  int row = gid >> 6, lane = gid & 63;
  if (row >= N_NODES) return;
  int b = rowptr[row], e = rowptr[row + 1];
  float acc = agg_row(esrc, m, b, e, lane);
  float dv = fmaxf((float)(e - b), 1.f);
  size_t o = (size_t)row * H_DIM + lane;
  float v = acc / dv + hr[o];
  float ss = v * v;
#pragma unroll
  for (int mm = 32; mm >= 1; mm >>= 1) ss += __shfl_xor(ss, mm, 64);
  zout[o] = v * rsqrtf(fmaxf(ss, 1e-30f));
}

// Decode: one thread per edge; 2 x 256B row reads, 64 FMA, softplus,
// wave+block reduce, one atomic per block.
__global__ __launch_bounds__(256) void decode_k(
    const int* __restrict__ ei, const float* __restrict__ z,
    float* __restrict__ loss)
{
  int e = blockIdx.x * 256 + threadIdx.x;
  float part = 0.f;
  if (e < N_EDGES) {
    int s = ei[e];
    int d = ei[N_EDGES + e];
    const float4* zs = (const float4*)(z + (size_t)s * H_DIM);
    const float4* zd = (const float4*)(z + (size_t)d * H_DIM);
    float p = 0.f;
#pragma unroll
    for (int k = 0; k < 16; ++k) {
      float4 a = zs[k], b = zd[k];
      p = fmaf(a.x, b.x, p); p = fmaf(a.y, b.y, p);
      p = fmaf(a.z, b.z, p); p = fmaf(a.w, b.w, p);
    }
    part = fmaxf(-p, 0.f) + log1pf(expf(-fabsf(p)));
  }
#pragma unroll
  for (int m = 32; m >= 1; m >>= 1) part += __shfl_xor(part, m, 64);
  __shared__ float sbuf[4];
  int lane = threadIdx.x & 63, w = threadIdx.x >> 6;
  if (lane == 0) sbuf[w] = part;
  __syncthreads();
  if (threadIdx.x == 0)
    atomicAdd(loss, sbuf[0] + sbuf[1] + sbuf[2] + sbuf[3]);
}

__global__ void fin_k(const float* __restrict__ loss, float* __restrict__ out)
{
  out[(size_t)N_NODES * H_DIM] = loss[0] / (float)N_EDGES;
}

extern "C" void kernel_launch(void* const* d_in, const int* in_sizes, int n_in,
                              void* d_out, int out_size, void* d_ws, size_t ws_size,
                              hipStream_t stream)
{
  (void)in_sizes; (void)n_in; (void)out_size; (void)ws_size;
  const float* x   = (const float*)d_in[0];
  const int*   ei  = (const int*)d_in[1];
  const float* W1l = (const float*)d_in[2];
  const float* b1l = (const float*)d_in[3];
  const float* W1r = (const float*)d_in[4];
  const float* W2l = (const float*)d_in[5];
  const float* b2l = (const float*)d_in[6];
  const float* W2r = (const float*)d_in[7];
  float* out = (float*)d_out;  // fp32: z [N*H] ++ loss [1]

  const size_t NH = (size_t)N_NODES * H_DIM;
  float* P      = (float*)d_ws;          // m1 -> m2
  float* Q      = P + NH;                // xr -> hr
  float* R      = Q + NH;                // h
  float* loss   = R + NH;
  int*   cnt    = (int*)(loss + 1);
  int*   rowptr = cnt + N_NODES;         // N+1
  int*   cursor = rowptr + N_NODES + 1;
  int*   esrc   = cursor + N_NODES;      // E

  hipMemsetAsync(cnt,  0, sizeof(int) * N_NODES, stream);
  hipMemsetAsync(loss, 0, sizeof(float), stream);

  dim3 blk(256);
  dim3 g_tile((N_NODES + 31) / 32);
  dim3 g_edge((N_EDGES + 255) / 256);
  dim3 g_node((N_NODES * 64 + 255) / 256);

  // CSR build
  hist_k<<<g_edge, blk, 0, stream>>>(ei, cnt);
  scan_k<<<dim3(1), dim3(1024), 0, stream>>>(cnt, rowptr, cursor);
  fill_k<<<g_edge, blk, 0, stream>>>(ei, cursor, esrc);
  // Layer 1
  gemm_tile_k<F_IN><<<g_tile, blk, 0, stream>>>(x, W1l, b1l, W1r, P, Q);
  agg1_k<<<g_node, blk, 0, stream>>>(rowptr, esrc, P, Q, R);
  // Layer 2
  gemm_tile_k<H_DIM><<<g_tile, blk, 0, stream>>>(R, W2l, b2l, W2r, P, Q);
  agg2_k<<<g_node, blk, 0, stream>>>(rowptr, esrc, P, Q, out);
  // Decode + loss
  decode_k<<<g_edge, blk, 0, stream>>>(ei, out, loss);
  fin_k<<<dim3(1), dim3(1), 0, stream>>>(loss, out);
}

// Round 7
// 438.652 us; speedup vs baseline: 2.4685x; 1.2699x over previous
//
#include <hip/hip_runtime.h>

// Problem constants (SVGA_7318624272625)
#define N_NODES 50000
#define N_EDGES 800000
#define F_IN    256
#define H_DIM   64
#define NB_SCAN ((N_NODES + 255) / 256)   // 196 scan blocks

// Tiled dual-GEMM: outl = X@Wl + bl, outr = X@Wr.  X:[N,K], W:[K,64].
// Block = 256 thr = 4 waves; block tiles 32 rows (LDS-staged), each wave
// computes 8 rows x 64 cols for BOTH W's -> 16 FMA per W-load pair.
// R5 lesson: K=64 full unroll spilled (VGPR=256, 234MB scratch writes);
// unroll 2 + launch_bounds(256,4) caps VGPR.
template<int K>
__global__ __launch_bounds__(256, 4) void gemm_tile_k(
    const float* __restrict__ X,
    const float* __restrict__ Wl,
    const float* __restrict__ bl,
    const float* __restrict__ Wr,
    float* __restrict__ outl, float* __restrict__ outr)
{
  __shared__ float xs[32][K];           // K=256: 32 KB, K=64: 8 KB
  const int row0 = blockIdx.x * 32;
  const int nvec   = 32 * K / 4;
  const int totvec = N_NODES * K / 4;
  const float4* Xv = (const float4*)X;
  float4* xsv = (float4*)&xs[0][0];
  const int base = row0 * (K / 4);
  for (int i = threadIdx.x; i < nvec; i += 256) {
    int gi = base + i;
    xsv[i] = (gi < totvec) ? Xv[gi] : make_float4(0.f, 0.f, 0.f, 0.f);
  }
  __syncthreads();
  const int lane = threadIdx.x & 63;
  const int r0   = (threadIdx.x >> 6) * 8;
  float accl[8], accr[8];
#pragma unroll
  for (int r = 0; r < 8; ++r) { accl[r] = 0.f; accr[r] = 0.f; }
#pragma unroll 2
  for (int k4 = 0; k4 < K; k4 += 4) {
    float4 xv[8];
#pragma unroll
    for (int r = 0; r < 8; ++r) xv[r] = *(const float4*)&xs[r0 + r][k4];  // broadcast
#pragma unroll
    for (int j = 0; j < 4; ++j) {
      float wl = Wl[(k4 + j) * H_DIM + lane];
      float wr = Wr[(k4 + j) * H_DIM + lane];
#pragma unroll
      for (int r = 0; r < 8; ++r) {
        float xx = (j == 0) ? xv[r].x : (j == 1) ? xv[r].y : (j == 2) ? xv[r].z : xv[r].w;
        accl[r] = fmaf(xx, wl, accl[r]);
        accr[r] = fmaf(xx, wr, accr[r]);
      }
    }
  }
  float bias = bl[lane];
#pragma unroll
  for (int r = 0; r < 8; ++r) {
    int row = row0 + r0 + r;
    if (row < N_NODES) {
      outl[(size_t)row * H_DIM + lane] = accl[r] + bias;
      outr[(size_t)row * H_DIM + lane] = accr[r];
    }
  }
}

// ---- CSR build ----
__global__ __launch_bounds__(256) void hist_k(const int* __restrict__ ei,
                                              int* __restrict__ cnt)
{
  int e = blockIdx.x * 256 + threadIdx.x;
  if (e >= N_EDGES) return;
  atomicAdd(&cnt[ei[N_EDGES + e]], 1);
}

// Multi-block exclusive scan (R6: single-block scan was 126us at 0.15% occ).
// Phase 1: per-block sums.
__global__ __launch_bounds__(256) void scan1_k(const int* __restrict__ cnt,
                                               int* __restrict__ bsum)
{
  __shared__ int s[256];
  int idx = blockIdx.x * 256 + threadIdx.x;
  s[threadIdx.x] = (idx < N_NODES) ? cnt[idx] : 0;
  __syncthreads();
#pragma unroll
  for (int off = 128; off > 0; off >>= 1) {
    if (threadIdx.x < off) s[threadIdx.x] += s[threadIdx.x + off];
    __syncthreads();
  }
  if (threadIdx.x == 0) bsum[blockIdx.x] = s[0];
}

// Phase 2: scan the 196 block sums (one small block).
__global__ __launch_bounds__(256) void scan2_k(const int* __restrict__ bsum,
                                               int* __restrict__ boff)
{
  __shared__ int s[256];
  int t = threadIdx.x;
  int v = (t < NB_SCAN) ? bsum[t] : 0;
  s[t] = v;
  __syncthreads();
  for (int off = 1; off < 256; off <<= 1) {
    int u = (t >= off) ? s[t - off] : 0;
    __syncthreads();
    s[t] += u;
    __syncthreads();
  }
  if (t < NB_SCAN) boff[t] = s[t] - v;   // exclusive
}

// Phase 3: local inclusive scan + block offset -> rowptr & cursor.
__global__ __launch_bounds__(256) void scan3_k(const int* __restrict__ cnt,
                                               const int* __restrict__ boff,
                                               int* __restrict__ rowptr,
                                               int* __restrict__ cursor)
{
  __shared__ int s[256];
  int idx = blockIdx.x * 256 + threadIdx.x;
  int t = threadIdx.x;
  int v = (idx < N_NODES) ? cnt[idx] : 0;
  s[t] = v;
  __syncthreads();
  for (int off = 1; off < 256; off <<= 1) {
    int u = (t >= off) ? s[t - off] : 0;
    __syncthreads();
    s[t] += u;
    __syncthreads();
  }
  int excl = boff[blockIdx.x] + s[t] - v;
  if (idx < N_NODES) { rowptr[idx] = excl; cursor[idx] = excl; }
  if (idx == N_NODES - 1) rowptr[N_NODES] = excl + v;   // == E
}

__global__ __launch_bounds__(256) void fill_k(const int* __restrict__ ei,
                                              int* __restrict__ cursor,
                                              int* __restrict__ esrc)
{
  int e = blockIdx.x * 256 + threadIdx.x;
  if (e >= N_EDGES) return;
  int s = ei[e], d = ei[N_EDGES + e];
  int pos = atomicAdd(&cursor[d], 1);
  esrc[pos] = s;
}

// ---- Fused aggregation: wave per dst node, lane = feature ----
// 4-way unrolled neighbor loop: independent index loads + parallel row
// gathers per iteration (4-deep memory-level parallelism).
__device__ __forceinline__ float agg_row(const int* __restrict__ esrc,
                                         const float* __restrict__ m,
                                         int b, int e, int lane)
{
  float a0 = 0.f, a1 = 0.f, a2 = 0.f, a3 = 0.f;
  int i = b;
  for (; i + 4 <= e; i += 4) {
    int s0 = esrc[i], s1 = esrc[i + 1], s2 = esrc[i + 2], s3 = esrc[i + 3];
    a0 += m[(size_t)s0 * H_DIM + lane];
    a1 += m[(size_t)s1 * H_DIM + lane];
    a2 += m[(size_t)s2 * H_DIM + lane];
    a3 += m[(size_t)s3 * H_DIM + lane];
  }
  for (; i < e; ++i) a0 += m[(size_t)esrc[i] * H_DIM + lane];
  return (a0 + a1) + (a2 + a3);
}

// h = relu(mean_{s in row} m[s] + xr)
__global__ __launch_bounds__(256) void agg1_k(
    const int* __restrict__ rowptr, const int* __restrict__ esrc,
    const float* __restrict__ m, const float* __restrict__ xr,
    float* __restrict__ h)
{
  int gid = blockIdx.x * 256 + threadIdx.x;
  int row = gid >> 6, lane = gid & 63;
  if (row >= N_NODES) return;
  int b = rowptr[row], e = rowptr[row + 1];
  float acc = agg_row(esrc, m, b, e, lane);
  float dv = fmaxf((float)(e - b), 1.f);
  size_t o = (size_t)row * H_DIM + lane;
  h[o] = fmaxf(acc / dv + xr[o], 0.f);
}

// z = unitnorm(mean m2 + hr), straight into d_out
__global__ __launch_bounds__(256) void agg2_k(
    const int* __restrict__ rowptr, const int* __restrict__ esrc,
    const float* __restrict__ m, const float* __restrict__ hr,
    float* __restrict__ zout)
{
  int gid = blockIdx.x * 256 + threadIdx.x;
  int row = gid >> 6, lane = gid & 63;
  if (row >= N_NODES) return;
  int b = rowptr[row], e = rowptr[row + 1];
  float acc = agg_row(esrc, m, b, e, lane);
  float dv = fmaxf((float)(e - b), 1.f);
  size_t o = (size_t)row * H_DIM + lane;
  float v = acc / dv + hr[o];
  float ss = v * v;
#pragma unroll
  for (int mm = 32; mm >= 1; mm >>= 1) ss += __shfl_xor(ss, mm, 64);
  zout[o] = v * rsqrtf(fmaxf(ss, 1e-30f));
}

// Decode: one thread per edge; 2 x 256B row reads, 64 FMA, softplus,
// wave+block reduce, one atomic per block.
__global__ __launch_bounds__(256) void decode_k(
    const int* __restrict__ ei, const float* __restrict__ z,
    float* __restrict__ loss)
{
  int e = blockIdx.x * 256 + threadIdx.x;
  float part = 0.f;
  if (e < N_EDGES) {
    int s = ei[e];
    int d = ei[N_EDGES + e];
    const float4* zs = (const float4*)(z + (size_t)s * H_DIM);
    const float4* zd = (const float4*)(z + (size_t)d * H_DIM);
    float p = 0.f;
#pragma unroll
    for (int k = 0; k < 16; ++k) {
      float4 a = zs[k], b = zd[k];
      p = fmaf(a.x, b.x, p); p = fmaf(a.y, b.y, p);
      p = fmaf(a.z, b.z, p); p = fmaf(a.w, b.w, p);
    }
    part = fmaxf(-p, 0.f) + log1pf(expf(-fabsf(p)));
  }
#pragma unroll
  for (int m = 32; m >= 1; m >>= 1) part += __shfl_xor(part, m, 64);
  __shared__ float sbuf[4];
  int lane = threadIdx.x & 63, w = threadIdx.x >> 6;
  if (lane == 0) sbuf[w] = part;
  __syncthreads();
  if (threadIdx.x == 0)
    atomicAdd(loss, sbuf[0] + sbuf[1] + sbuf[2] + sbuf[3]);
}

__global__ void fin_k(const float* __restrict__ loss, float* __restrict__ out)
{
  out[(size_t)N_NODES * H_DIM] = loss[0] / (float)N_EDGES;
}

extern "C" void kernel_launch(void* const* d_in, const int* in_sizes, int n_in,
                              void* d_out, int out_size, void* d_ws, size_t ws_size,
                              hipStream_t stream)
{
  (void)in_sizes; (void)n_in; (void)out_size; (void)ws_size;
  const float* x   = (const float*)d_in[0];
  const int*   ei  = (const int*)d_in[1];
  const float* W1l = (const float*)d_in[2];
  const float* b1l = (const float*)d_in[3];
  const float* W1r = (const float*)d_in[4];
  const float* W2l = (const float*)d_in[5];
  const float* b2l = (const float*)d_in[6];
  const float* W2r = (const float*)d_in[7];
  float* out = (float*)d_out;  // fp32: z [N*H] ++ loss [1]

  const size_t NH = (size_t)N_NODES * H_DIM;
  float* P      = (float*)d_ws;          // m1 -> m2
  float* Q      = P + NH;                // xr -> hr
  float* R      = Q + NH;                // h
  float* loss   = R + NH;
  int*   cnt    = (int*)(loss + 1);
  int*   rowptr = cnt + N_NODES;         // N+1
  int*   cursor = rowptr + N_NODES + 1;
  int*   esrc   = cursor + N_NODES;      // E
  int*   bsum   = esrc + N_EDGES;        // NB_SCAN
  int*   boff   = bsum + NB_SCAN;        // NB_SCAN

  hipMemsetAsync(cnt,  0, sizeof(int) * N_NODES, stream);
  hipMemsetAsync(loss, 0, sizeof(float), stream);

  dim3 blk(256);
  dim3 g_tile((N_NODES + 31) / 32);
  dim3 g_edge((N_EDGES + 255) / 256);
  dim3 g_node((N_NODES * 64 + 255) / 256);
  dim3 g_scan(NB_SCAN);

  // CSR build (multi-block scan)
  hist_k<<<g_edge, blk, 0, stream>>>(ei, cnt);
  scan1_k<<<g_scan, blk, 0, stream>>>(cnt, bsum);
  scan2_k<<<dim3(1), blk, 0, stream>>>(bsum, boff);
  scan3_k<<<g_scan, blk, 0, stream>>>(cnt, boff, rowptr, cursor);
  fill_k<<<g_edge, blk, 0, stream>>>(ei, cursor, esrc);
  // Layer 1
  gemm_tile_k<F_IN><<<g_tile, blk, 0, stream>>>(x, W1l, b1l, W1r, P, Q);
  agg1_k<<<g_node, blk, 0, stream>>>(rowptr, esrc, P, Q, R);
  // Layer 2
  gemm_tile_k<H_DIM><<<g_tile, blk, 0, stream>>>(R, W2l, b2l, W2r, P, Q);
  agg2_k<<<g_node, blk, 0, stream>>>(rowptr, esrc, P, Q, out);
  // Decode + loss
  decode_k<<<g_edge, blk, 0, stream>>>(ei, out, loss);
  fin_k<<<dim3(1), dim3(1), 0, stream>>>(loss, out);
}

// Round 8
// 389.539 us; speedup vs baseline: 2.7797x; 1.1261x over previous
//
#include <hip/hip_runtime.h>

// Problem constants (SVGA_7318624272625)
#define N_NODES 50000
#define N_EDGES 800000
#define F_IN    256
#define H_DIM   64
#define NB_SCAN ((N_NODES + 255) / 256)   // 196 scan blocks

typedef __attribute__((ext_vector_type(8))) short short8;
typedef __attribute__((ext_vector_type(4))) float floatx4;

__device__ __forceinline__ unsigned short f2bf(float f) {  // RNE fp32->bf16
  unsigned int u;
  __builtin_memcpy(&u, &f, 4);
  u += 0x7fffu + ((u >> 16) & 1u);
  return (unsigned short)(u >> 16);
}

// Pack W[K,64] (fp32) -> bf16 MFMA B-fragments.
// Frag id f = (ks*4 + c)*2 + m ; lane L, j holds B[k=ks*32+(L>>4)*8+j][n=c*16+(L&15)].
// Stored as uint4 per (f,lane): Wb[f*64 + lane].
template<int K>
__global__ __launch_bounds__(256) void pack_w_k(
    const float* __restrict__ Wl, const float* __restrict__ Wr,
    unsigned short* __restrict__ Wb)
{
  int t = blockIdx.x * 256 + threadIdx.x;
  const int total = (K / 32) * 4 * 2 * 64;
  if (t >= total) return;
  int lane = t & 63;
  int f    = t >> 6;
  int m    = f & 1;
  int c    = (f >> 1) & 3;
  int ks   = f >> 3;
  const float* W = m ? Wr : Wl;
  int quad = lane >> 4, l15 = lane & 15;
  int col = c * 16 + l15;
  unsigned short u[8];
#pragma unroll
  for (int j = 0; j < 8; ++j) {
    int k = ks * 32 + quad * 8 + j;
    u[j] = f2bf(W[k * H_DIM + col]);
  }
  uint4 v;
  __builtin_memcpy(&v, u, 16);
  ((uint4*)Wb)[t] = v;
}

// MFMA dual-GEMM: outl = X@Wl + bl, outr = X@Wr.  X:[N,K] fp32, W pre-packed bf16.
// Block = 256 thr = 4 waves, 64 rows/block (16 rows/wave).  X staged to LDS as
// bf16, row pad +8 (stride 528B for K=256 -> 2-way bank alias = free).
template<int K>
__global__ __launch_bounds__(256, 4) void gemm_mfma_k(
    const float* __restrict__ X,
    const unsigned short* __restrict__ Wb,
    const float* __restrict__ bl,
    float* __restrict__ outl, float* __restrict__ outr)
{
  constexpr int KP = K + 8;                 // padded row length (bf16 units)
  __shared__ unsigned short xs[64 * KP];
  const int row0 = blockIdx.x * 64;
  const int CH = K / 4;                     // float4 chunks per row
  for (int i = threadIdx.x; i < 64 * CH; i += 256) {
    int r = i / CH, c = i % CH;
    int row = row0 + r;
    float4 v = (row < N_NODES) ? ((const float4*)X)[(size_t)row * CH + c]
                               : make_float4(0.f, 0.f, 0.f, 0.f);
    unsigned int lo = (unsigned int)f2bf(v.x) | ((unsigned int)f2bf(v.y) << 16);
    unsigned int hi = (unsigned int)f2bf(v.z) | ((unsigned int)f2bf(v.w) << 16);
    *(uint2*)&xs[r * KP + c * 4] = make_uint2(lo, hi);
  }
  __syncthreads();

  const int lane = threadIdx.x & 63;
  const int w    = threadIdx.x >> 6;
  const int quad = lane >> 4;
  const int l15  = lane & 15;
  const int rloc = w * 16 + l15;            // A-frag row (A[m=lane&15][k=quad*8+j])

  floatx4 accl[4], accr[4];
#pragma unroll
  for (int c = 0; c < 4; ++c) { accl[c] = (floatx4)0.f; accr[c] = (floatx4)0.f; }

  const uint4* wbase = (const uint4*)Wb;
#pragma unroll
  for (int ks = 0; ks < K / 32; ++ks) {
    short8 af = *(const short8*)&xs[rloc * KP + ks * 32 + quad * 8];
#pragma unroll
    for (int c = 0; c < 4; ++c) {
      uint4 rl = wbase[((ks * 4 + c) * 2 + 0) * 64 + lane];
      uint4 rr = wbase[((ks * 4 + c) * 2 + 1) * 64 + lane];
      short8 bfl, bfr;
      __builtin_memcpy(&bfl, &rl, 16);
      __builtin_memcpy(&bfr, &rr, 16);
      accl[c] = __builtin_amdgcn_mfma_f32_16x16x32_bf16(af, bfl, accl[c], 0, 0, 0);
      accr[c] = __builtin_amdgcn_mfma_f32_16x16x32_bf16(af, bfr, accr[c], 0, 0, 0);
    }
  }
  // C/D: col = c*16 + (lane&15), tile row = quad*4 + reg
#pragma unroll
  for (int c = 0; c < 4; ++c) {
    int col = c * 16 + l15;
    float bias = bl[col];
#pragma unroll
    for (int reg = 0; reg < 4; ++reg) {
      int row = row0 + w * 16 + quad * 4 + reg;
      if (row < N_NODES) {
        outl[(size_t)row * H_DIM + col] = accl[c][reg] + bias;
        outr[(size_t)row * H_DIM + col] = accr[c][reg];
      }
    }
  }
}

// ---- CSR build ----
__global__ __launch_bounds__(256) void hist_k(const int* __restrict__ ei,
                                              int* __restrict__ cnt)
{
  int e = blockIdx.x * 256 + threadIdx.x;
  if (e >= N_EDGES) return;
  atomicAdd(&cnt[ei[N_EDGES + e]], 1);
}

// Multi-block exclusive scan. Phase 1: per-block sums.
__global__ __launch_bounds__(256) void scan1_k(const int* __restrict__ cnt,
                                               int* __restrict__ bsum)
{
  __shared__ int s[256];
  int idx = blockIdx.x * 256 + threadIdx.x;
  s[threadIdx.x] = (idx < N_NODES) ? cnt[idx] : 0;
  __syncthreads();
#pragma unroll
  for (int off = 128; off > 0; off >>= 1) {
    if (threadIdx.x < off) s[threadIdx.x] += s[threadIdx.x + off];
    __syncthreads();
  }
  if (threadIdx.x == 0) bsum[blockIdx.x] = s[0];
}

// Phase 2: scan the 196 block sums (one small block).
__global__ __launch_bounds__(256) void scan2_k(const int* __restrict__ bsum,
                                               int* __restrict__ boff)
{
  __shared__ int s[256];
  int t = threadIdx.x;
  int v = (t < NB_SCAN) ? bsum[t] : 0;
  s[t] = v;
  __syncthreads();
  for (int off = 1; off < 256; off <<= 1) {
    int u = (t >= off) ? s[t - off] : 0;
    __syncthreads();
    s[t] += u;
    __syncthreads();
  }
  if (t < NB_SCAN) boff[t] = s[t] - v;   // exclusive
}

// Phase 3: local inclusive scan + block offset -> rowptr & cursor.
__global__ __launch_bounds__(256) void scan3_k(const int* __restrict__ cnt,
                                               const int* __restrict__ boff,
                                               int* __restrict__ rowptr,
                                               int* __restrict__ cursor)
{
  __shared__ int s[256];
  int idx = blockIdx.x * 256 + threadIdx.x;
  int t = threadIdx.x;
  int v = (idx < N_NODES) ? cnt[idx] : 0;
  s[t] = v;
  __syncthreads();
  for (int off = 1; off < 256; off <<= 1) {
    int u = (t >= off) ? s[t - off] : 0;
    __syncthreads();
    s[t] += u;
    __syncthreads();
  }
  int excl = boff[blockIdx.x] + s[t] - v;
  if (idx < N_NODES) { rowptr[idx] = excl; cursor[idx] = excl; }
  if (idx == N_NODES - 1) rowptr[N_NODES] = excl + v;   // == E
}

__global__ __launch_bounds__(256) void fill_k(const int* __restrict__ ei,
                                              int* __restrict__ cursor,
                                              int* __restrict__ esrc)
{
  int e = blockIdx.x * 256 + threadIdx.x;
  if (e >= N_EDGES) return;
  int s = ei[e], d = ei[N_EDGES + e];
  int pos = atomicAdd(&cursor[d], 1);
  esrc[pos] = s;
}

// ---- Fused aggregation: wave per dst node, lane = feature ----
__device__ __forceinline__ float agg_row(const int* __restrict__ esrc,
                                         const float* __restrict__ m,
                                         int b, int e, int lane)
{
  float a0 = 0.f, a1 = 0.f, a2 = 0.f, a3 = 0.f;
  int i = b;
  for (; i + 4 <= e; i += 4) {
    int s0 = esrc[i], s1 = esrc[i + 1], s2 = esrc[i + 2], s3 = esrc[i + 3];
    a0 += m[(size_t)s0 * H_DIM + lane];
    a1 += m[(size_t)s1 * H_DIM + lane];
    a2 += m[(size_t)s2 * H_DIM + lane];
    a3 += m[(size_t)s3 * H_DIM + lane];
  }
  for (; i < e; ++i) a0 += m[(size_t)esrc[i] * H_DIM + lane];
  return (a0 + a1) + (a2 + a3);
}

// h = relu(mean_{s in row} m[s] + xr)
__global__ __launch_bounds__(256) void agg1_k(
    const int* __restrict__ rowptr, const int* __restrict__ esrc,
    const float* __restrict__ m, const float* __restrict__ xr,
    float* __restrict__ h)
{
  int gid = blockIdx.x * 256 + threadIdx.x;
  int row = gid >> 6, lane = gid & 63;
  if (row >= N_NODES) return;
  int b = rowptr[row], e = rowptr[row + 1];
  float acc = agg_row(esrc, m, b, e, lane);
  float dv = fmaxf((float)(e - b), 1.f);
  size_t o = (size_t)row * H_DIM + lane;
  h[o] = fmaxf(acc / dv + xr[o], 0.f);
}

// z = unitnorm(mean m2 + hr), straight into d_out
__global__ __launch_bounds__(256) void agg2_k(
    const int* __restrict__ rowptr, const int* __restrict__ esrc,
    const float* __restrict__ m, const float* __restrict__ hr,
    float* __restrict__ zout)
{
  int gid = blockIdx.x * 256 + threadIdx.x;
  int row = gid >> 6, lane = gid & 63;
  if (row >= N_NODES) return;
  int b = rowptr[row], e = rowptr[row + 1];
  float acc = agg_row(esrc, m, b, e, lane);
  float dv = fmaxf((float)(e - b), 1.f);
  size_t o = (size_t)row * H_DIM + lane;
  float v = acc / dv + hr[o];
  float ss = v * v;
#pragma unroll
  for (int mm = 32; mm >= 1; mm >>= 1) ss += __shfl_xor(ss, mm, 64);
  zout[o] = v * rsqrtf(fmaxf(ss, 1e-30f));
}

// Decode: one thread per edge; 2 x 256B row reads, 64 FMA, softplus,
// wave+block reduce, one atomic per block.
__global__ __launch_bounds__(256) void decode_k(
    const int* __restrict__ ei, const float* __restrict__ z,
    float* __restrict__ loss)
{
  int e = blockIdx.x * 256 + threadIdx.x;
  float part = 0.f;
  if (e < N_EDGES) {
    int s = ei[e];
    int d = ei[N_EDGES + e];
    const float4* zs = (const float4*)(z + (size_t)s * H_DIM);
    const float4* zd = (const float4*)(z + (size_t)d * H_DIM);
    float p = 0.f;
#pragma unroll
    for (int k = 0; k < 16; ++k) {
      float4 a = zs[k], b = zd[k];
      p = fmaf(a.x, b.x, p); p = fmaf(a.y, b.y, p);
      p = fmaf(a.z, b.z, p); p = fmaf(a.w, b.w, p);
    }
    part = fmaxf(-p, 0.f) + log1pf(expf(-fabsf(p)));
  }
#pragma unroll
  for (int m = 32; m >= 1; m >>= 1) part += __shfl_xor(part, m, 64);
  __shared__ float sbuf[4];
  int lane = threadIdx.x & 63, w = threadIdx.x >> 6;
  if (lane == 0) sbuf[w] = part;
  __syncthreads();
  if (threadIdx.x == 0)
    atomicAdd(loss, sbuf[0] + sbuf[1] + sbuf[2] + sbuf[3]);
}

__global__ void fin_k(const float* __restrict__ loss, float* __restrict__ out)
{
  out[(size_t)N_NODES * H_DIM] = loss[0] / (float)N_EDGES;
}

extern "C" void kernel_launch(void* const* d_in, const int* in_sizes, int n_in,
                              void* d_out, int out_size, void* d_ws, size_t ws_size,
                              hipStream_t stream)
{
  (void)in_sizes; (void)n_in; (void)out_size; (void)ws_size;
  const float* x   = (const float*)d_in[0];
  const int*   ei  = (const int*)d_in[1];
  const float* W1l = (const float*)d_in[2];
  const float* b1l = (const float*)d_in[3];
  const float* W1r = (const float*)d_in[4];
  const float* W2l = (const float*)d_in[5];
  const float* b2l = (const float*)d_in[6];
  const float* W2r = (const float*)d_in[7];
  float* out = (float*)d_out;  // fp32: z [N*H] ++ loss [1]

  const size_t NH = (size_t)N_NODES * H_DIM;
  float* P      = (float*)d_ws;          // m1 -> m2
  float* Q      = P + NH;                // xr -> hr
  float* R      = Q + NH;                // h
  float* loss   = R + NH;
  int*   cnt    = (int*)(loss + 1);
  int*   rowptr = cnt + N_NODES;         // N+1
  int*   cursor = rowptr + N_NODES + 1;
  int*   esrc   = cursor + N_NODES;      // E
  int*   bsum   = esrc + N_EDGES;        // NB_SCAN
  int*   boff   = bsum + NB_SCAN;        // NB_SCAN
  unsigned short* Wb1 = (unsigned short*)(boff + NB_SCAN);  // 256/32*4*2*64 uint4 = 64 KB
  unsigned short* Wb2 = Wb1 + (F_IN / 32) * 4 * 2 * 64 * 8; // 16 KB

  hipMemsetAsync(cnt,  0, sizeof(int) * N_NODES, stream);
  hipMemsetAsync(loss, 0, sizeof(float), stream);

  dim3 blk(256);
  dim3 g_tile((N_NODES + 63) / 64);
  dim3 g_edge((N_EDGES + 255) / 256);
  dim3 g_node((N_NODES * 64 + 255) / 256);
  dim3 g_scan(NB_SCAN);

  // W fragment pack (bf16)
  pack_w_k<F_IN><<<dim3(16), blk, 0, stream>>>(W1l, W1r, Wb1);
  pack_w_k<H_DIM><<<dim3(4),  blk, 0, stream>>>(W2l, W2r, Wb2);
  // CSR build (multi-block scan)
  hist_k<<<g_edge, blk, 0, stream>>>(ei, cnt);
  scan1_k<<<g_scan, blk, 0, stream>>>(cnt, bsum);
  scan2_k<<<dim3(1), blk, 0, stream>>>(bsum, boff);
  scan3_k<<<g_scan, blk, 0, stream>>>(cnt, boff, rowptr, cursor);
  fill_k<<<g_edge, blk, 0, stream>>>(ei, cursor, esrc);
  // Layer 1 (MFMA)
  gemm_mfma_k<F_IN><<<g_tile, blk, 0, stream>>>(x, Wb1, b1l, P, Q);
  agg1_k<<<g_node, blk, 0, stream>>>(rowptr, esrc, P, Q, R);
  // Layer 2 (MFMA)
  gemm_mfma_k<H_DIM><<<g_tile, blk, 0, stream>>>(R, Wb2, b2l, P, Q);
  agg2_k<<<g_node, blk, 0, stream>>>(rowptr, esrc, P, Q, out);
  // Decode + loss
  decode_k<<<g_edge, blk, 0, stream>>>(ei, out, loss);
  fin_k<<<dim3(1), dim3(1), 0, stream>>>(loss, out);
}

// Round 10
// 357.794 us; speedup vs baseline: 3.0263x; 1.0887x over previous
//
#include <hip/hip_runtime.h>

// Problem constants (SVGA_7318624272625)
#define N_NODES 50000
#define N_EDGES 800000
#define F_IN    256
#define H_DIM   64
#define NB_SCAN ((N_NODES + 255) / 256)   // 196 scan blocks

typedef __attribute__((ext_vector_type(8))) short short8;
typedef __attribute__((ext_vector_type(4))) float floatx4;

__device__ __forceinline__ unsigned short f2bf(float f) {  // RNE fp32->bf16
  unsigned int u;
  __builtin_memcpy(&u, &f, 4);
  u += 0x7fffu + ((u >> 16) & 1u);
  return (unsigned short)(u >> 16);
}
__device__ __forceinline__ float bflo(unsigned int u) {  // low bf16 of packed pair
  unsigned int v = u << 16; float f; __builtin_memcpy(&f, &v, 4); return f;
}
__device__ __forceinline__ float bfhi(unsigned int u) {  // high bf16
  unsigned int v = u & 0xffff0000u; float f; __builtin_memcpy(&f, &v, 4); return f;
}

// Pack W[K,64] (fp32) -> bf16 MFMA B-fragments.
// Frag id f = (ks*4 + c)*2 + m ; lane L, j holds B[k=ks*32+(L>>4)*8+j][n=c*16+(L&15)].
template<int K>
__global__ __launch_bounds__(256) void pack_w_k(
    const float* __restrict__ Wl, const float* __restrict__ Wr,
    unsigned short* __restrict__ Wb)
{
  int t = blockIdx.x * 256 + threadIdx.x;
  const int total = (K / 32) * 4 * 2 * 64;
  if (t >= total) return;
  int lane = t & 63;
  int f    = t >> 6;
  int m    = f & 1;
  int c    = (f >> 1) & 3;
  int ks   = f >> 3;
  const float* W = m ? Wr : Wl;
  int quad = lane >> 4, l15 = lane & 15;
  int col = c * 16 + l15;
  unsigned short u[8];
#pragma unroll
  for (int j = 0; j < 8; ++j) {
    int k = ks * 32 + quad * 8 + j;
    u[j] = f2bf(W[k * H_DIM + col]);
  }
  uint4 v;
  __builtin_memcpy(&v, u, 16);
  ((uint4*)Wb)[t] = v;
}

// MFMA dual-GEMM: outl = X@Wl + bl, outr = X@Wr.  X:[N,K] fp32, W pre-packed bf16.
// Block = 4 waves, 64 rows/block (16 rows/wave).  X staged to LDS as bf16,
// row pad +8.
template<int K>
__global__ __launch_bounds__(256, 4) void gemm_mfma_k(
    const float* __restrict__ X,
    const unsigned short* __restrict__ Wb,
    const float* __restrict__ bl,
    float* __restrict__ outl, float* __restrict__ outr)
{
  constexpr int KP = K + 8;                 // padded row length (bf16 units)
  __shared__ unsigned short xs[64 * KP];
  const int row0 = blockIdx.x * 64;
  const int CH = K / 4;                     // float4 chunks per row
  for (int i = threadIdx.x; i < 64 * CH; i += 256) {
    int r = i / CH, c = i % CH;
    int row = row0 + r;
    float4 v = (row < N_NODES) ? ((const float4*)X)[(size_t)row * CH + c]
                               : make_float4(0.f, 0.f, 0.f, 0.f);
    unsigned int lo = (unsigned int)f2bf(v.x) | ((unsigned int)f2bf(v.y) << 16);
    unsigned int hi = (unsigned int)f2bf(v.z) | ((unsigned int)f2bf(v.w) << 16);
    *(uint2*)&xs[r * KP + c * 4] = make_uint2(lo, hi);
  }
  __syncthreads();

  const int lane = threadIdx.x & 63;
  const int w    = threadIdx.x >> 6;
  const int quad = lane >> 4;
  const int l15  = lane & 15;
  const int rloc = w * 16 + l15;            // A-frag row

  floatx4 accl[4], accr[4];
#pragma unroll
  for (int c = 0; c < 4; ++c) { accl[c] = (floatx4)0.f; accr[c] = (floatx4)0.f; }

  const uint4* wbase = (const uint4*)Wb;
#pragma unroll
  for (int ks = 0; ks < K / 32; ++ks) {
    short8 af = *(const short8*)&xs[rloc * KP + ks * 32 + quad * 8];
#pragma unroll
    for (int c = 0; c < 4; ++c) {
      uint4 rl = wbase[((ks * 4 + c) * 2 + 0) * 64 + lane];
      uint4 rr = wbase[((ks * 4 + c) * 2 + 1) * 64 + lane];
      short8 bfl, bfr;
      __builtin_memcpy(&bfl, &rl, 16);
      __builtin_memcpy(&bfr, &rr, 16);
      accl[c] = __builtin_amdgcn_mfma_f32_16x16x32_bf16(af, bfl, accl[c], 0, 0, 0);
      accr[c] = __builtin_amdgcn_mfma_f32_16x16x32_bf16(af, bfr, accr[c], 0, 0, 0);
    }
  }
#pragma unroll
  for (int c = 0; c < 4; ++c) {
    int col = c * 16 + l15;
    float bias = bl[col];
#pragma unroll
    for (int reg = 0; reg < 4; ++reg) {
      int row = row0 + w * 16 + quad * 4 + reg;
      if (row < N_NODES) {
        outl[(size_t)row * H_DIM + col] = accl[c][reg] + bias;
        outr[(size_t)row * H_DIM + col] = accr[c][reg];
      }
    }
  }
}

// ---- CSR build ----
__global__ __launch_bounds__(256) void hist_k(const int* __restrict__ ei,
                                              int* __restrict__ cnt)
{
  int e = blockIdx.x * 256 + threadIdx.x;
  if (e >= N_EDGES) return;
  atomicAdd(&cnt[ei[N_EDGES + e]], 1);
}

__global__ __launch_bounds__(256) void scan1_k(const int* __restrict__ cnt,
                                               int* __restrict__ bsum)
{
  __shared__ int s[256];
  int idx = blockIdx.x * 256 + threadIdx.x;
  s[threadIdx.x] = (idx < N_NODES) ? cnt[idx] : 0;
  __syncthreads();
#pragma unroll
  for (int off = 128; off > 0; off >>= 1) {
    if (threadIdx.x < off) s[threadIdx.x] += s[threadIdx.x + off];
    __syncthreads();
  }
  if (threadIdx.x == 0) bsum[blockIdx.x] = s[0];
}

__global__ __launch_bounds__(256) void scan2_k(const int* __restrict__ bsum,
                                               int* __restrict__ boff)
{
  __shared__ int s[256];
  int t = threadIdx.x;
  int v = (t < NB_SCAN) ? bsum[t] : 0;
  s[t] = v;
  __syncthreads();
  for (int off = 1; off < 256; off <<= 1) {
    int u = (t >= off) ? s[t - off] : 0;
    __syncthreads();
    s[t] += u;
    __syncthreads();
  }
  if (t < NB_SCAN) boff[t] = s[t] - v;   // exclusive
}

__global__ __launch_bounds__(256) void scan3_k(const int* __restrict__ cnt,
                                               const int* __restrict__ boff,
                                               int* __restrict__ rowptr,
                                               int* __restrict__ cursor)
{
  __shared__ int s[256];
  int idx = blockIdx.x * 256 + threadIdx.x;
  int t = threadIdx.x;
  int v = (idx < N_NODES) ? cnt[idx] : 0;
  s[t] = v;
  __syncthreads();
  for (int off = 1; off < 256; off <<= 1) {
    int u = (t >= off) ? s[t - off] : 0;
    __syncthreads();
    s[t] += u;
    __syncthreads();
  }
  int excl = boff[blockIdx.x] + s[t] - v;
  if (idx < N_NODES) { rowptr[idx] = excl; cursor[idx] = excl; }
  if (idx == N_NODES - 1) rowptr[N_NODES] = excl + v;   // == E
}

// fill: also record dst per CSR slot (for CSR-ordered decode)
__global__ __launch_bounds__(256) void fill_k(const int* __restrict__ ei,
                                              int* __restrict__ cursor,
                                              int* __restrict__ esrc,
                                              int* __restrict__ edst)
{
  int e = blockIdx.x * 256 + threadIdx.x;
  if (e >= N_EDGES) return;
  int s = ei[e], d = ei[N_EDGES + e];
  int pos = atomicAdd(&cursor[d], 1);
  esrc[pos] = s;
  edst[pos] = d;
}

// ---- Fused aggregation: wave per dst node, lane = feature ----
__device__ __forceinline__ float agg_row(const int* __restrict__ esrc,
                                         const float* __restrict__ m,
                                         int b, int e, int lane)
{
  float a0 = 0.f, a1 = 0.f, a2 = 0.f, a3 = 0.f;
  int i = b;
  for (; i + 4 <= e; i += 4) {
    int s0 = esrc[i], s1 = esrc[i + 1], s2 = esrc[i + 2], s3 = esrc[i + 3];
    a0 += m[(size_t)s0 * H_DIM + lane];
    a1 += m[(size_t)s1 * H_DIM + lane];
    a2 += m[(size_t)s2 * H_DIM + lane];
    a3 += m[(size_t)s3 * H_DIM + lane];
  }
  for (; i < e; ++i) a0 += m[(size_t)esrc[i] * H_DIM + lane];
  return (a0 + a1) + (a2 + a3);
}

// h = relu(mean_{s in row} m[s] + xr)
__global__ __launch_bounds__(256) void agg1_k(
    const int* __restrict__ rowptr, const int* __restrict__ esrc,
    const float* __restrict__ m, const float* __restrict__ xr,
    float* __restrict__ h)
{
  int gid = blockIdx.x * 256 + threadIdx.x;
  int row = gid >> 6, lane = gid & 63;
  if (row >= N_NODES) return;
  int b = rowptr[row], e = rowptr[row + 1];
  float acc = agg_row(esrc, m, b, e, lane);
  float dv = fmaxf((float)(e - b), 1.f);
  size_t o = (size_t)row * H_DIM + lane;
  h[o] = fmaxf(acc / dv + xr[o], 0.f);
}

// z = unitnorm(mean m2 + hr) -> fp32 d_out + bf16 copy (for decode gathers)
__global__ __launch_bounds__(256) void agg2_k(
    const int* __restrict__ rowptr, const int* __restrict__ esrc,
    const float* __restrict__ m, const float* __restrict__ hr,
    float* __restrict__ zout, unsigned short* __restrict__ zb)
{
  int gid = blockIdx.x * 256 + threadIdx.x;
  int row = gid >> 6, lane = gid & 63;
  if (row >= N_NODES) return;
  int b = rowptr[row], e = rowptr[row + 1];
  float acc = agg_row(esrc, m, b, e, lane);
  float dv = fmaxf((float)(e - b), 1.f);
  size_t o = (size_t)row * H_DIM + lane;
  float v = acc / dv + hr[o];
  float ss = v * v;
#pragma unroll
  for (int mm = 32; mm >= 1; mm >>= 1) ss += __shfl_xor(ss, mm, 64);
  float z = v * rsqrtf(fmaxf(ss, 1e-30f));
  zout[o] = z;
  zb[o] = f2bf(z);
}

// Decode v2: thread per CSR slot (dst-sorted -> consecutive threads share the
// dst row), bf16 z rows.  R9 bug: row = 64 bf16 = 8 uint4, loop ran k<4 and
// dropped half the dot -> loss off by 0.055.  Fixed: k<8.
__global__ __launch_bounds__(256) void decode2_k(
    const int* __restrict__ esrc, const int* __restrict__ edst,
    const unsigned short* __restrict__ zb, float* __restrict__ loss)
{
  int i = blockIdx.x * 256 + threadIdx.x;
  float part = 0.f;
  if (i < N_EDGES) {
    int s = esrc[i];
    int d = edst[i];
    const uint4* zs = (const uint4*)(zb + (size_t)s * H_DIM);
    const uint4* zd = (const uint4*)(zb + (size_t)d * H_DIM);
    float p = 0.f;
#pragma unroll
    for (int k = 0; k < 8; ++k) {          // 8 uint4 = 64 bf16 = full row
      uint4 a = zs[k], b = zd[k];
      unsigned int au[4] = {a.x, a.y, a.z, a.w};
      unsigned int bu[4] = {b.x, b.y, b.z, b.w};
#pragma unroll
      for (int j = 0; j < 4; ++j) {
        p = fmaf(bflo(au[j]), bflo(bu[j]), p);
        p = fmaf(bfhi(au[j]), bfhi(bu[j]), p);
      }
    }
    part = fmaxf(-p, 0.f) + log1pf(expf(-fabsf(p)));
  }
#pragma unroll
  for (int m = 32; m >= 1; m >>= 1) part += __shfl_xor(part, m, 64);
  __shared__ float sbuf[4];
  int lane = threadIdx.x & 63, w = threadIdx.x >> 6;
  if (lane == 0) sbuf[w] = part;
  __syncthreads();
  if (threadIdx.x == 0)
    atomicAdd(loss, sbuf[0] + sbuf[1] + sbuf[2] + sbuf[3]);
}

__global__ void fin_k(const float* __restrict__ loss, float* __restrict__ out)
{
  out[(size_t)N_NODES * H_DIM] = loss[0] / (float)N_EDGES;
}

extern "C" void kernel_launch(void* const* d_in, const int* in_sizes, int n_in,
                              void* d_out, int out_size, void* d_ws, size_t ws_size,
                              hipStream_t stream)
{
  (void)in_sizes; (void)n_in; (void)out_size; (void)ws_size;
  const float* x   = (const float*)d_in[0];
  const int*   ei  = (const int*)d_in[1];
  const float* W1l = (const float*)d_in[2];
  const float* b1l = (const float*)d_in[3];
  const float* W1r = (const float*)d_in[4];
  const float* W2l = (const float*)d_in[5];
  const float* b2l = (const float*)d_in[6];
  const float* W2r = (const float*)d_in[7];
  float* out = (float*)d_out;  // fp32: z [N*H] ++ loss [1]

  const size_t NH = (size_t)N_NODES * H_DIM;
  float* P      = (float*)d_ws;          // m1 -> m2
  float* Q      = P + NH;                // xr -> hr
  float* R      = Q + NH;                // h
  float* loss   = R + NH;
  int*   cnt    = (int*)(loss + 1);
  int*   rowptr = cnt + N_NODES;         // N+1
  int*   cursor = rowptr + N_NODES + 1;
  int*   esrc   = cursor + N_NODES;      // E
  int*   edst   = esrc + N_EDGES;        // E
  int*   bsum   = edst + N_EDGES;        // NB_SCAN
  int*   boff   = bsum + NB_SCAN;        // NB_SCAN
  unsigned short* Wb1 = (unsigned short*)(boff + NB_SCAN);   // 64 KB
  unsigned short* Wb2 = Wb1 + (F_IN / 32) * 4 * 2 * 64 * 8;  // 16 KB
  unsigned short* zb  = Wb2 + (H_DIM / 32) * 4 * 2 * 64 * 8; // N*H bf16

  hipMemsetAsync(cnt,  0, sizeof(int) * N_NODES, stream);
  hipMemsetAsync(loss, 0, sizeof(float), stream);

  dim3 blk(256);
  dim3 g_tile((N_NODES + 63) / 64);
  dim3 g_edge((N_EDGES + 255) / 256);
  dim3 g_node((N_NODES * 64 + 255) / 256);
  dim3 g_scan(NB_SCAN);

  // W fragment pack (bf16)
  pack_w_k<F_IN><<<dim3(16), blk, 0, stream>>>(W1l, W1r, Wb1);
  pack_w_k<H_DIM><<<dim3(4),  blk, 0, stream>>>(W2l, W2r, Wb2);
  // CSR build (multi-block scan)
  hist_k<<<g_edge, blk, 0, stream>>>(ei, cnt);
  scan1_k<<<g_scan, blk, 0, stream>>>(cnt, bsum);
  scan2_k<<<dim3(1), blk, 0, stream>>>(bsum, boff);
  scan3_k<<<g_scan, blk, 0, stream>>>(cnt, boff, rowptr, cursor);
  fill_k<<<g_edge, blk, 0, stream>>>(ei, cursor, esrc, edst);
  // Layer 1 (MFMA)
  gemm_mfma_k<F_IN><<<g_tile, blk, 0, stream>>>(x, Wb1, b1l, P, Q);
  agg1_k<<<g_node, blk, 0, stream>>>(rowptr, esrc, P, Q, R);
  // Layer 2 (MFMA)
  gemm_mfma_k<H_DIM><<<g_tile, blk, 0, stream>>>(R, Wb2, b2l, P, Q);
  agg2_k<<<g_node, blk, 0, stream>>>(rowptr, esrc, P, Q, out, zb);
  // Decode + loss (CSR order, bf16 gathers)
  decode2_k<<<g_edge, blk, 0, stream>>>(esrc, edst, zb, loss);
  fin_k<<<dim3(1), dim3(1), 0, stream>>>(loss, out);
}

// Round 11
// 348.193 us; speedup vs baseline: 3.1098x; 1.0276x over previous
//
#include <hip/hip_runtime.h>

// Problem constants (SVGA_7318624272625)
#define N_NODES 50000
#define N_EDGES 800000
#define F_IN    256
#define H_DIM   64
#define NB_SCAN ((N_NODES + 255) / 256)   // 196 scan blocks

typedef __attribute__((ext_vector_type(8))) short short8;
typedef __attribute__((ext_vector_type(4))) float floatx4;

__device__ __forceinline__ unsigned short f2bf(float f) {  // RNE fp32->bf16
  unsigned int u;
  __builtin_memcpy(&u, &f, 4);
  u += 0x7fffu + ((u >> 16) & 1u);
  return (unsigned short)(u >> 16);
}
__device__ __forceinline__ float bflo(unsigned int u) {  // low bf16 of packed pair
  unsigned int v = u << 16; float f; __builtin_memcpy(&f, &v, 4); return f;
}
__device__ __forceinline__ float bfhi(unsigned int u) {  // high bf16
  unsigned int v = u & 0xffff0000u; float f; __builtin_memcpy(&f, &v, 4); return f;
}

// Pack W[K,64] (fp32) -> bf16 MFMA B-fragments.
// Frag id f = (ks*4 + c)*2 + m ; lane L, j holds B[k=ks*32+(L>>4)*8+j][n=c*16+(L&15)].
template<int K>
__global__ __launch_bounds__(256) void pack_w_k(
    const float* __restrict__ Wl, const float* __restrict__ Wr,
    unsigned short* __restrict__ Wb)
{
  int t = blockIdx.x * 256 + threadIdx.x;
  const int total = (K / 32) * 4 * 2 * 64;
  if (t >= total) return;
  int lane = t & 63;
  int f    = t >> 6;
  int m    = f & 1;
  int c    = (f >> 1) & 3;
  int ks   = f >> 3;
  const float* W = m ? Wr : Wl;
  int quad = lane >> 4, l15 = lane & 15;
  int col = c * 16 + l15;
  unsigned short u[8];
#pragma unroll
  for (int j = 0; j < 8; ++j) {
    int k = ks * 32 + quad * 8 + j;
    u[j] = f2bf(W[k * H_DIM + col]);
  }
  uint4 v;
  __builtin_memcpy(&v, u, 16);
  ((uint4*)Wb)[t] = v;
}

// MFMA dual-GEMM: outl = X@Wl + bl, outr = X@Wr.  X:[N,K] fp32, W pre-packed bf16.
// Block = 4 waves, 64 rows/block (16 rows/wave).  X staged to LDS as bf16,
// row pad +8.
template<int K>
__global__ __launch_bounds__(256, 4) void gemm_mfma_k(
    const float* __restrict__ X,
    const unsigned short* __restrict__ Wb,
    const float* __restrict__ bl,
    float* __restrict__ outl, float* __restrict__ outr)
{
  constexpr int KP = K + 8;                 // padded row length (bf16 units)
  __shared__ unsigned short xs[64 * KP];
  const int row0 = blockIdx.x * 64;
  const int CH = K / 4;                     // float4 chunks per row
  for (int i = threadIdx.x; i < 64 * CH; i += 256) {
    int r = i / CH, c = i % CH;
    int row = row0 + r;
    float4 v = (row < N_NODES) ? ((const float4*)X)[(size_t)row * CH + c]
                               : make_float4(0.f, 0.f, 0.f, 0.f);
    unsigned int lo = (unsigned int)f2bf(v.x) | ((unsigned int)f2bf(v.y) << 16);
    unsigned int hi = (unsigned int)f2bf(v.z) | ((unsigned int)f2bf(v.w) << 16);
    *(uint2*)&xs[r * KP + c * 4] = make_uint2(lo, hi);
  }
  __syncthreads();

  const int lane = threadIdx.x & 63;
  const int w    = threadIdx.x >> 6;
  const int quad = lane >> 4;
  const int l15  = lane & 15;
  const int rloc = w * 16 + l15;            // A-frag row

  floatx4 accl[4], accr[4];
#pragma unroll
  for (int c = 0; c < 4; ++c) { accl[c] = (floatx4)0.f; accr[c] = (floatx4)0.f; }

  const uint4* wbase = (const uint4*)Wb;
#pragma unroll
  for (int ks = 0; ks < K / 32; ++ks) {
    short8 af = *(const short8*)&xs[rloc * KP + ks * 32 + quad * 8];
#pragma unroll
    for (int c = 0; c < 4; ++c) {
      uint4 rl = wbase[((ks * 4 + c) * 2 + 0) * 64 + lane];
      uint4 rr = wbase[((ks * 4 + c) * 2 + 1) * 64 + lane];
      short8 bfl, bfr;
      __builtin_memcpy(&bfl, &rl, 16);
      __builtin_memcpy(&bfr, &rr, 16);
      accl[c] = __builtin_amdgcn_mfma_f32_16x16x32_bf16(af, bfl, accl[c], 0, 0, 0);
      accr[c] = __builtin_amdgcn_mfma_f32_16x16x32_bf16(af, bfr, accr[c], 0, 0, 0);
    }
  }
#pragma unroll
  for (int c = 0; c < 4; ++c) {
    int col = c * 16 + l15;
    float bias = bl[col];
#pragma unroll
    for (int reg = 0; reg < 4; ++reg) {
      int row = row0 + w * 16 + quad * 4 + reg;
      if (row < N_NODES) {
        outl[(size_t)row * H_DIM + col] = accl[c][reg] + bias;
        outr[(size_t)row * H_DIM + col] = accr[c][reg];
      }
    }
  }
}

// ---- CSR build ----
__global__ __launch_bounds__(256) void hist_k(const int* __restrict__ ei,
                                              int* __restrict__ cnt)
{
  int e = blockIdx.x * 256 + threadIdx.x;
  if (e >= N_EDGES) return;
  atomicAdd(&cnt[ei[N_EDGES + e]], 1);
}

__global__ __launch_bounds__(256) void scan1_k(const int* __restrict__ cnt,
                                               int* __restrict__ bsum)
{
  __shared__ int s[256];
  int idx = blockIdx.x * 256 + threadIdx.x;
  s[threadIdx.x] = (idx < N_NODES) ? cnt[idx] : 0;
  __syncthreads();
#pragma unroll
  for (int off = 128; off > 0; off >>= 1) {
    if (threadIdx.x < off) s[threadIdx.x] += s[threadIdx.x + off];
    __syncthreads();
  }
  if (threadIdx.x == 0) bsum[blockIdx.x] = s[0];
}

__global__ __launch_bounds__(256) void scan2_k(const int* __restrict__ bsum,
                                               int* __restrict__ boff)
{
  __shared__ int s[256];
  int t = threadIdx.x;
  int v = (t < NB_SCAN) ? bsum[t] : 0;
  s[t] = v;
  __syncthreads();
  for (int off = 1; off < 256; off <<= 1) {
    int u = (t >= off) ? s[t - off] : 0;
    __syncthreads();
    s[t] += u;
    __syncthreads();
  }
  if (t < NB_SCAN) boff[t] = s[t] - v;   // exclusive
}

__global__ __launch_bounds__(256) void scan3_k(const int* __restrict__ cnt,
                                               const int* __restrict__ boff,
                                               int* __restrict__ rowptr,
                                               int* __restrict__ cursor)
{
  __shared__ int s[256];
  int idx = blockIdx.x * 256 + threadIdx.x;
  int t = threadIdx.x;
  int v = (idx < N_NODES) ? cnt[idx] : 0;
  s[t] = v;
  __syncthreads();
  for (int off = 1; off < 256; off <<= 1) {
    int u = (t >= off) ? s[t - off] : 0;
    __syncthreads();
    s[t] += u;
    __syncthreads();
  }
  int excl = boff[blockIdx.x] + s[t] - v;
  if (idx < N_NODES) { rowptr[idx] = excl; cursor[idx] = excl; }
  if (idx == N_NODES - 1) rowptr[N_NODES] = excl + v;   // == E
}

// fill: only esrc scatter (R10: dual scatter caused 83MB write-allocate; edst
// now generated sequentially by expand_k).
__global__ __launch_bounds__(256) void fill_k(const int* __restrict__ ei,
                                              int* __restrict__ cursor,
                                              int* __restrict__ esrc)
{
  int e = blockIdx.x * 256 + threadIdx.x;
  if (e >= N_EDGES) return;
  int s = ei[e], d = ei[N_EDGES + e];
  int pos = atomicAdd(&cursor[d], 1);
  esrc[pos] = s;
}

// expand rowptr -> edst: thread per node, sequential writes.
__global__ __launch_bounds__(256) void expand_k(const int* __restrict__ rowptr,
                                                int* __restrict__ edst)
{
  int n = blockIdx.x * 256 + threadIdx.x;
  if (n >= N_NODES) return;
  int b = rowptr[n], e = rowptr[n + 1];
  for (int i = b; i < e; ++i) edst[i] = n;
}

// ---- Fused aggregation: wave per dst node, lane = feature ----
__device__ __forceinline__ float agg_row(const int* __restrict__ esrc,
                                         const float* __restrict__ m,
                                         int b, int e, int lane)
{
  float a0 = 0.f, a1 = 0.f, a2 = 0.f, a3 = 0.f;
  int i = b;
  for (; i + 4 <= e; i += 4) {
    int s0 = esrc[i], s1 = esrc[i + 1], s2 = esrc[i + 2], s3 = esrc[i + 3];
    a0 += m[(size_t)s0 * H_DIM + lane];
    a1 += m[(size_t)s1 * H_DIM + lane];
    a2 += m[(size_t)s2 * H_DIM + lane];
    a3 += m[(size_t)s3 * H_DIM + lane];
  }
  for (; i < e; ++i) a0 += m[(size_t)esrc[i] * H_DIM + lane];
  return (a0 + a1) + (a2 + a3);
}

// h = relu(mean_{s in row} m[s] + xr)
__global__ __launch_bounds__(256) void agg1_k(
    const int* __restrict__ rowptr, const int* __restrict__ esrc,
    const float* __restrict__ m, const float* __restrict__ xr,
    float* __restrict__ h)
{
  int gid = blockIdx.x * 256 + threadIdx.x;
  int row = gid >> 6, lane = gid & 63;
  if (row >= N_NODES) return;
  int b = rowptr[row], e = rowptr[row + 1];
  float acc = agg_row(esrc, m, b, e, lane);
  float dv = fmaxf((float)(e - b), 1.f);
  size_t o = (size_t)row * H_DIM + lane;
  h[o] = fmaxf(acc / dv + xr[o], 0.f);
}

// z = unitnorm(mean m2 + hr) -> fp32 d_out + bf16 copy (for decode gathers)
__global__ __launch_bounds__(256) void agg2_k(
    const int* __restrict__ rowptr, const int* __restrict__ esrc,
    const float* __restrict__ m, const float* __restrict__ hr,
    float* __restrict__ zout, unsigned short* __restrict__ zb)
{
  int gid = blockIdx.x * 256 + threadIdx.x;
  int row = gid >> 6, lane = gid & 63;
  if (row >= N_NODES) return;
  int b = rowptr[row], e = rowptr[row + 1];
  float acc = agg_row(esrc, m, b, e, lane);
  float dv = fmaxf((float)(e - b), 1.f);
  size_t o = (size_t)row * H_DIM + lane;
  float v = acc / dv + hr[o];
  float ss = v * v;
#pragma unroll
  for (int mm = 32; mm >= 1; mm >>= 1) ss += __shfl_xor(ss, mm, 64);
  float z = v * rsqrtf(fmaxf(ss, 1e-30f));
  zout[o] = z;
  zb[o] = f2bf(z);
}

// Decode v3: two edges per thread (4 row-gathers in flight), CSR order,
// bf16 z rows.  N_EDGES even -> pair always valid when first index valid.
__global__ __launch_bounds__(256) void decode2_k(
    const int* __restrict__ esrc, const int* __restrict__ edst,
    const unsigned short* __restrict__ zb, float* __restrict__ loss)
{
  int i0 = (blockIdx.x * 256 + threadIdx.x) * 2;
  float part = 0.f;
  if (i0 + 1 < N_EDGES) {
    int s0 = esrc[i0],     d0 = edst[i0];
    int s1 = esrc[i0 + 1], d1 = edst[i0 + 1];
    const uint4* zs0 = (const uint4*)(zb + (size_t)s0 * H_DIM);
    const uint4* zd0 = (const uint4*)(zb + (size_t)d0 * H_DIM);
    const uint4* zs1 = (const uint4*)(zb + (size_t)s1 * H_DIM);
    const uint4* zd1 = (const uint4*)(zb + (size_t)d1 * H_DIM);
    float p0 = 0.f, p1 = 0.f;
#pragma unroll 4
    for (int k = 0; k < 8; ++k) {          // 8 uint4 = 64 bf16 = full row
      uint4 a0 = zs0[k], b0 = zd0[k], a1 = zs1[k], b1 = zd1[k];
      unsigned int au0[4] = {a0.x, a0.y, a0.z, a0.w};
      unsigned int bu0[4] = {b0.x, b0.y, b0.z, b0.w};
      unsigned int au1[4] = {a1.x, a1.y, a1.z, a1.w};
      unsigned int bu1[4] = {b1.x, b1.y, b1.z, b1.w};
#pragma unroll
      for (int j = 0; j < 4; ++j) {
        p0 = fmaf(bflo(au0[j]), bflo(bu0[j]), p0);
        p0 = fmaf(bfhi(au0[j]), bfhi(bu0[j]), p0);
        p1 = fmaf(bflo(au1[j]), bflo(bu1[j]), p1);
        p1 = fmaf(bfhi(au1[j]), bfhi(bu1[j]), p1);
      }
    }
    part  = fmaxf(-p0, 0.f) + log1pf(expf(-fabsf(p0)));
    part += fmaxf(-p1, 0.f) + log1pf(expf(-fabsf(p1)));
  }
#pragma unroll
  for (int m = 32; m >= 1; m >>= 1) part += __shfl_xor(part, m, 64);
  __shared__ float sbuf[4];
  int lane = threadIdx.x & 63, w = threadIdx.x >> 6;
  if (lane == 0) sbuf[w] = part;
  __syncthreads();
  if (threadIdx.x == 0)
    atomicAdd(loss, sbuf[0] + sbuf[1] + sbuf[2] + sbuf[3]);
}

__global__ void fin_k(const float* __restrict__ loss, float* __restrict__ out)
{
  out[(size_t)N_NODES * H_DIM] = loss[0] / (float)N_EDGES;
}

extern "C" void kernel_launch(void* const* d_in, const int* in_sizes, int n_in,
                              void* d_out, int out_size, void* d_ws, size_t ws_size,
                              hipStream_t stream)
{
  (void)in_sizes; (void)n_in; (void)out_size; (void)ws_size;
  const float* x   = (const float*)d_in[0];
  const int*   ei  = (const int*)d_in[1];
  const float* W1l = (const float*)d_in[2];
  const float* b1l = (const float*)d_in[3];
  const float* W1r = (const float*)d_in[4];
  const float* W2l = (const float*)d_in[5];
  const float* b2l = (const float*)d_in[6];
  const float* W2r = (const float*)d_in[7];
  float* out = (float*)d_out;  // fp32: z [N*H] ++ loss [1]

  const size_t NH = (size_t)N_NODES * H_DIM;
  float* P      = (float*)d_ws;          // m1 -> m2
  float* Q      = P + NH;                // xr -> hr
  float* R      = Q + NH;                // h
  float* loss   = R + NH;
  int*   cnt    = (int*)(loss + 1);
  int*   rowptr = cnt + N_NODES;         // N+1
  int*   cursor = rowptr + N_NODES + 1;
  int*   esrc   = cursor + N_NODES;      // E
  int*   edst   = esrc + N_EDGES;        // E
  int*   bsum   = edst + N_EDGES;        // NB_SCAN
  int*   boff   = bsum + NB_SCAN;        // NB_SCAN
  unsigned short* Wb1 = (unsigned short*)(boff + NB_SCAN);   // 64 KB
  unsigned short* Wb2 = Wb1 + (F_IN / 32) * 4 * 2 * 64 * 8;  // 16 KB
  unsigned short* zb  = Wb2 + (H_DIM / 32) * 4 * 2 * 64 * 8; // N*H bf16

  hipMemsetAsync(cnt,  0, sizeof(int) * N_NODES, stream);
  hipMemsetAsync(loss, 0, sizeof(float), stream);

  dim3 blk(256);
  dim3 g_tile((N_NODES + 63) / 64);
  dim3 g_edge((N_EDGES + 255) / 256);
  dim3 g_edge2((N_EDGES / 2 + 255) / 256);
  dim3 g_node((N_NODES * 64 + 255) / 256);
  dim3 g_nthr((N_NODES + 255) / 256);
  dim3 g_scan(NB_SCAN);

  // W fragment pack (bf16)
  pack_w_k<F_IN><<<dim3(16), blk, 0, stream>>>(W1l, W1r, Wb1);
  pack_w_k<H_DIM><<<dim3(4),  blk, 0, stream>>>(W2l, W2r, Wb2);
  // CSR build (multi-block scan)
  hist_k<<<g_edge, blk, 0, stream>>>(ei, cnt);
  scan1_k<<<g_scan, blk, 0, stream>>>(cnt, bsum);
  scan2_k<<<dim3(1), blk, 0, stream>>>(bsum, boff);
  scan3_k<<<g_scan, blk, 0, stream>>>(cnt, boff, rowptr, cursor);
  fill_k<<<g_edge, blk, 0, stream>>>(ei, cursor, esrc);
  expand_k<<<g_nthr, blk, 0, stream>>>(rowptr, edst);
  // Layer 1 (MFMA)
  gemm_mfma_k<F_IN><<<g_tile, blk, 0, stream>>>(x, Wb1, b1l, P, Q);
  agg1_k<<<g_node, blk, 0, stream>>>(rowptr, esrc, P, Q, R);
  // Layer 2 (MFMA)
  gemm_mfma_k<H_DIM><<<g_tile, blk, 0, stream>>>(R, Wb2, b2l, P, Q);
  agg2_k<<<g_node, blk, 0, stream>>>(rowptr, esrc, P, Q, out, zb);
  // Decode + loss (CSR order, bf16 gathers, 2 edges/thread)
  decode2_k<<<g_edge2, blk, 0, stream>>>(esrc, edst, zb, loss);
  fin_k<<<dim3(1), dim3(1), 0, stream>>>(loss, out);
}

// Round 12
// 339.573 us; speedup vs baseline: 3.1887x; 1.0254x over previous
//
#include <hip/hip_runtime.h>

// Problem constants (SVGA_7318624272625)
#define N_NODES 50000
#define N_EDGES 800000
#define F_IN    256
#define H_DIM   64
#define NB_SCAN ((N_NODES + 255) / 256)   // 196 scan blocks

typedef __attribute__((ext_vector_type(8))) short short8;
typedef __attribute__((ext_vector_type(4))) float floatx4;

__device__ __forceinline__ unsigned short f2bf(float f) {  // RNE fp32->bf16
  unsigned int u;
  __builtin_memcpy(&u, &f, 4);
  u += 0x7fffu + ((u >> 16) & 1u);
  return (unsigned short)(u >> 16);
}
__device__ __forceinline__ float bf2f(unsigned short s) {
  unsigned int v = ((unsigned int)s) << 16; float f; __builtin_memcpy(&f, &v, 4); return f;
}
__device__ __forceinline__ float bflo(unsigned int u) {
  unsigned int v = u << 16; float f; __builtin_memcpy(&f, &v, 4); return f;
}
__device__ __forceinline__ float bfhi(unsigned int u) {
  unsigned int v = u & 0xffff0000u; float f; __builtin_memcpy(&f, &v, 4); return f;
}

// Pack W[K,64] (fp32) -> bf16 MFMA B-fragments.
// Frag id f = (ks*4 + c)*2 + m ; lane L, j holds B[k=ks*32+(L>>4)*8+j][n=c*16+(L&15)].
template<int K>
__global__ __launch_bounds__(256) void pack_w_k(
    const float* __restrict__ Wl, const float* __restrict__ Wr,
    unsigned short* __restrict__ Wb)
{
  int t = blockIdx.x * 256 + threadIdx.x;
  const int total = (K / 32) * 4 * 2 * 64;
  if (t >= total) return;
  int lane = t & 63;
  int f    = t >> 6;
  int m    = f & 1;
  int c    = (f >> 1) & 3;
  int ks   = f >> 3;
  const float* W = m ? Wr : Wl;
  int quad = lane >> 4, l15 = lane & 15;
  int col = c * 16 + l15;
  unsigned short u[8];
#pragma unroll
  for (int j = 0; j < 8; ++j) {
    int k = ks * 32 + quad * 8 + j;
    u[j] = f2bf(W[k * H_DIM + col]);
  }
  uint4 v;
  __builtin_memcpy(&v, u, 16);
  ((uint4*)Wb)[t] = v;
}

// MFMA dual-GEMM: outl = bf16(X@Wl + bl)  (gathered later -> bf16 halves traffic),
// outr = fp32(X@Wr) (read coalesced later).  X fp32 (layer1) or bf16 (layer2).
template<int K, bool XBF16>
__global__ __launch_bounds__(256, 4) void gemm_mfma_k(
    const void* __restrict__ X_,
    const unsigned short* __restrict__ Wb,
    const float* __restrict__ bl,
    unsigned short* __restrict__ outl, float* __restrict__ outr)
{
  constexpr int KP = K + 8;                 // padded row length (bf16 units)
  __shared__ unsigned short xs[64 * KP];
  const int row0 = blockIdx.x * 64;
  if (XBF16) {
    const uint4* X = (const uint4*)X_;      // row = K bf16 = K/8 uint4
    const int CH = K / 8;
    for (int i = threadIdx.x; i < 64 * CH; i += 256) {
      int r = i / CH, c = i % CH;
      int row = row0 + r;
      uint4 v = (row < N_NODES) ? X[(size_t)row * CH + c] : make_uint4(0, 0, 0, 0);
      *(uint4*)&xs[r * KP + c * 8] = v;
    }
  } else {
    const float4* X = (const float4*)X_;
    const int CH = K / 4;
    for (int i = threadIdx.x; i < 64 * CH; i += 256) {
      int r = i / CH, c = i % CH;
      int row = row0 + r;
      float4 v = (row < N_NODES) ? X[(size_t)row * CH + c]
                                 : make_float4(0.f, 0.f, 0.f, 0.f);
      unsigned int lo = (unsigned int)f2bf(v.x) | ((unsigned int)f2bf(v.y) << 16);
      unsigned int hi = (unsigned int)f2bf(v.z) | ((unsigned int)f2bf(v.w) << 16);
      *(uint2*)&xs[r * KP + c * 4] = make_uint2(lo, hi);
    }
  }
  __syncthreads();

  const int lane = threadIdx.x & 63;
  const int w    = threadIdx.x >> 6;
  const int quad = lane >> 4;
  const int l15  = lane & 15;
  const int rloc = w * 16 + l15;            // A-frag row

  floatx4 accl[4], accr[4];
#pragma unroll
  for (int c = 0; c < 4; ++c) { accl[c] = (floatx4)0.f; accr[c] = (floatx4)0.f; }

  const uint4* wbase = (const uint4*)Wb;
#pragma unroll
  for (int ks = 0; ks < K / 32; ++ks) {
    short8 af = *(const short8*)&xs[rloc * KP + ks * 32 + quad * 8];
#pragma unroll
    for (int c = 0; c < 4; ++c) {
      uint4 rl = wbase[((ks * 4 + c) * 2 + 0) * 64 + lane];
      uint4 rr = wbase[((ks * 4 + c) * 2 + 1) * 64 + lane];
      short8 bfl, bfr;
      __builtin_memcpy(&bfl, &rl, 16);
      __builtin_memcpy(&bfr, &rr, 16);
      accl[c] = __builtin_amdgcn_mfma_f32_16x16x32_bf16(af, bfl, accl[c], 0, 0, 0);
      accr[c] = __builtin_amdgcn_mfma_f32_16x16x32_bf16(af, bfr, accr[c], 0, 0, 0);
    }
  }
#pragma unroll
  for (int c = 0; c < 4; ++c) {
    int col = c * 16 + l15;
    float bias = bl[col];
#pragma unroll
    for (int reg = 0; reg < 4; ++reg) {
      int row = row0 + w * 16 + quad * 4 + reg;
      if (row < N_NODES) {
        outl[(size_t)row * H_DIM + col] = f2bf(accl[c][reg] + bias);
        outr[(size_t)row * H_DIM + col] = accr[c][reg];
      }
    }
  }
}

// ---- CSR build ----
__global__ __launch_bounds__(256) void hist_k(const int* __restrict__ ei,
                                              int* __restrict__ cnt)
{
  int e = blockIdx.x * 256 + threadIdx.x;
  if (e >= N_EDGES) return;
  atomicAdd(&cnt[ei[N_EDGES + e]], 1);
}

__global__ __launch_bounds__(256) void scan1_k(const int* __restrict__ cnt,
                                               int* __restrict__ bsum)
{
  __shared__ int s[256];
  int idx = blockIdx.x * 256 + threadIdx.x;
  s[threadIdx.x] = (idx < N_NODES) ? cnt[idx] : 0;
  __syncthreads();
#pragma unroll
  for (int off = 128; off > 0; off >>= 1) {
    if (threadIdx.x < off) s[threadIdx.x] += s[threadIdx.x + off];
    __syncthreads();
  }
  if (threadIdx.x == 0) bsum[blockIdx.x] = s[0];
}

__global__ __launch_bounds__(256) void scan2_k(const int* __restrict__ bsum,
                                               int* __restrict__ boff)
{
  __shared__ int s[256];
  int t = threadIdx.x;
  int v = (t < NB_SCAN) ? bsum[t] : 0;
  s[t] = v;
  __syncthreads();
  for (int off = 1; off < 256; off <<= 1) {
    int u = (t >= off) ? s[t - off] : 0;
    __syncthreads();
    s[t] += u;
    __syncthreads();
  }
  if (t < NB_SCAN) boff[t] = s[t] - v;   // exclusive
}

__global__ __launch_bounds__(256) void scan3_k(const int* __restrict__ cnt,
                                               const int* __restrict__ boff,
                                               int* __restrict__ rowptr,
                                               int* __restrict__ cursor)
{
  __shared__ int s[256];
  int idx = blockIdx.x * 256 + threadIdx.x;
  int t = threadIdx.x;
  int v = (idx < N_NODES) ? cnt[idx] : 0;
  s[t] = v;
  __syncthreads();
  for (int off = 1; off < 256; off <<= 1) {
    int u = (t >= off) ? s[t - off] : 0;
    __syncthreads();
    s[t] += u;
    __syncthreads();
  }
  int excl = boff[blockIdx.x] + s[t] - v;
  if (idx < N_NODES) { rowptr[idx] = excl; cursor[idx] = excl; }
  if (idx == N_NODES - 1) rowptr[N_NODES] = excl + v;   // == E
}

// fill: esrc scatter only (edst generated sequentially by expand_k)
__global__ __launch_bounds__(256) void fill_k(const int* __restrict__ ei,
                                              int* __restrict__ cursor,
                                              int* __restrict__ esrc)
{
  int e = blockIdx.x * 256 + threadIdx.x;
  if (e >= N_EDGES) return;
  int s = ei[e], d = ei[N_EDGES + e];
  int pos = atomicAdd(&cursor[d], 1);
  esrc[pos] = s;
}

// expand rowptr -> edst: thread per node, sequential writes.
__global__ __launch_bounds__(256) void expand_k(const int* __restrict__ rowptr,
                                                int* __restrict__ edst)
{
  int n = blockIdx.x * 256 + threadIdx.x;
  if (n >= N_NODES) return;
  int b = rowptr[n], e = rowptr[n + 1];
  for (int i = b; i < e; ++i) edst[i] = n;
}

// ---- Fused aggregation: wave per dst node, lane = feature, bf16 messages ----
__device__ __forceinline__ float agg_row_b(const int* __restrict__ esrc,
                                           const unsigned short* __restrict__ m,
                                           int b, int e, int lane)
{
  float a0 = 0.f, a1 = 0.f, a2 = 0.f, a3 = 0.f;
  int i = b;
  for (; i + 4 <= e; i += 4) {
    int s0 = esrc[i], s1 = esrc[i + 1], s2 = esrc[i + 2], s3 = esrc[i + 3];
    a0 += bf2f(m[(size_t)s0 * H_DIM + lane]);
    a1 += bf2f(m[(size_t)s1 * H_DIM + lane]);
    a2 += bf2f(m[(size_t)s2 * H_DIM + lane]);
    a3 += bf2f(m[(size_t)s3 * H_DIM + lane]);
  }
  for (; i < e; ++i) a0 += bf2f(m[(size_t)esrc[i] * H_DIM + lane]);
  return (a0 + a1) + (a2 + a3);
}

// h = relu(mean m1 + xr) -> bf16 (gemm2 stages bf16 anyway: no extra rounding)
__global__ __launch_bounds__(256) void agg1_k(
    const int* __restrict__ rowptr, const int* __restrict__ esrc,
    const unsigned short* __restrict__ m, const float* __restrict__ xr,
    unsigned short* __restrict__ h)
{
  int gid = blockIdx.x * 256 + threadIdx.x;
  int row = gid >> 6, lane = gid & 63;
  if (row >= N_NODES) return;
  int b = rowptr[row], e = rowptr[row + 1];
  float acc = agg_row_b(esrc, m, b, e, lane);
  float dv = fmaxf((float)(e - b), 1.f);
  size_t o = (size_t)row * H_DIM + lane;
  h[o] = f2bf(fmaxf(acc / dv + xr[o], 0.f));
}

// z = unitnorm(mean m2 + hr) -> fp32 d_out + bf16 copy (for decode gathers)
__global__ __launch_bounds__(256) void agg2_k(
    const int* __restrict__ rowptr, const int* __restrict__ esrc,
    const unsigned short* __restrict__ m, const float* __restrict__ hr,
    float* __restrict__ zout, unsigned short* __restrict__ zb)
{
  int gid = blockIdx.x * 256 + threadIdx.x;
  int row = gid >> 6, lane = gid & 63;
  if (row >= N_NODES) return;
  int b = rowptr[row], e = rowptr[row + 1];
  float acc = agg_row_b(esrc, m, b, e, lane);
  float dv = fmaxf((float)(e - b), 1.f);
  size_t o = (size_t)row * H_DIM + lane;
  float v = acc / dv + hr[o];
  float ss = v * v;
#pragma unroll
  for (int mm = 32; mm >= 1; mm >>= 1) ss += __shfl_xor(ss, mm, 64);
  float z = v * rsqrtf(fmaxf(ss, 1e-30f));
  zout[o] = z;
  zb[o] = f2bf(z);
}

// Decode: two edges per thread, CSR order, bf16 z rows.
__global__ __launch_bounds__(256) void decode2_k(
    const int* __restrict__ esrc, const int* __restrict__ edst,
    const unsigned short* __restrict__ zb, float* __restrict__ loss)
{
  int i0 = (blockIdx.x * 256 + threadIdx.x) * 2;
  float part = 0.f;
  if (i0 + 1 < N_EDGES) {
    int s0 = esrc[i0],     d0 = edst[i0];
    int s1 = esrc[i0 + 1], d1 = edst[i0 + 1];
    const uint4* zs0 = (const uint4*)(zb + (size_t)s0 * H_DIM);
    const uint4* zd0 = (const uint4*)(zb + (size_t)d0 * H_DIM);
    const uint4* zs1 = (const uint4*)(zb + (size_t)s1 * H_DIM);
    const uint4* zd1 = (const uint4*)(zb + (size_t)d1 * H_DIM);
    float p0 = 0.f, p1 = 0.f;
#pragma unroll 4
    for (int k = 0; k < 8; ++k) {          // 8 uint4 = 64 bf16 = full row
      uint4 a0 = zs0[k], b0 = zd0[k], a1 = zs1[k], b1 = zd1[k];
      unsigned int au0[4] = {a0.x, a0.y, a0.z, a0.w};
      unsigned int bu0[4] = {b0.x, b0.y, b0.z, b0.w};
      unsigned int au1[4] = {a1.x, a1.y, a1.z, a1.w};
      unsigned int bu1[4] = {b1.x, b1.y, b1.z, b1.w};
#pragma unroll
      for (int j = 0; j < 4; ++j) {
        p0 = fmaf(bflo(au0[j]), bflo(bu0[j]), p0);
        p0 = fmaf(bfhi(au0[j]), bfhi(bu0[j]), p0);
        p1 = fmaf(bflo(au1[j]), bflo(bu1[j]), p1);
        p1 = fmaf(bfhi(au1[j]), bfhi(bu1[j]), p1);
      }
    }
    part  = fmaxf(-p0, 0.f) + log1pf(expf(-fabsf(p0)));
    part += fmaxf(-p1, 0.f) + log1pf(expf(-fabsf(p1)));
  }
#pragma unroll
  for (int m = 32; m >= 1; m >>= 1) part += __shfl_xor(part, m, 64);
  __shared__ float sbuf[4];
  int lane = threadIdx.x & 63, w = threadIdx.x >> 6;
  if (lane == 0) sbuf[w] = part;
  __syncthreads();
  if (threadIdx.x == 0)
    atomicAdd(loss, sbuf[0] + sbuf[1] + sbuf[2] + sbuf[3]);
}

__global__ void fin_k(const float* __restrict__ loss, float* __restrict__ out)
{
  out[(size_t)N_NODES * H_DIM] = loss[0] / (float)N_EDGES;
}

extern "C" void kernel_launch(void* const* d_in, const int* in_sizes, int n_in,
                              void* d_out, int out_size, void* d_ws, size_t ws_size,
                              hipStream_t stream)
{
  (void)in_sizes; (void)n_in; (void)out_size; (void)ws_size;
  const float* x   = (const float*)d_in[0];
  const int*   ei  = (const int*)d_in[1];
  const float* W1l = (const float*)d_in[2];
  const float* b1l = (const float*)d_in[3];
  const float* W1r = (const float*)d_in[4];
  const float* W2l = (const float*)d_in[5];
  const float* b2l = (const float*)d_in[6];
  const float* W2r = (const float*)d_in[7];
  float* out = (float*)d_out;  // fp32: z [N*H] ++ loss [1]

  const size_t NH = (size_t)N_NODES * H_DIM;
  // Buffer reuse: uA = m1 then m2 (bf16); fA = xr then hr (fp32);
  //               uB = h then zb (bf16).
  unsigned short* uA = (unsigned short*)d_ws;   // NH ushort
  unsigned short* uB = uA + NH;                 // NH ushort
  float* fA     = (float*)(uB + NH);            // NH float
  float* loss   = fA + NH;
  int*   cnt    = (int*)(loss + 1);
  int*   rowptr = cnt + N_NODES;         // N+1
  int*   cursor = rowptr + N_NODES + 1;
  int*   esrc   = cursor + N_NODES;      // E
  int*   edst   = esrc + N_EDGES;        // E
  int*   bsum   = edst + N_EDGES;        // NB_SCAN
  int*   boff   = bsum + NB_SCAN;        // NB_SCAN
  unsigned short* Wb1 = (unsigned short*)(boff + NB_SCAN);   // 64 KB
  unsigned short* Wb2 = Wb1 + (F_IN / 32) * 4 * 2 * 64 * 8;  // 16 KB

  hipMemsetAsync(cnt,  0, sizeof(int) * N_NODES, stream);
  hipMemsetAsync(loss, 0, sizeof(float), stream);

  dim3 blk(256);
  dim3 g_tile((N_NODES + 63) / 64);
  dim3 g_edge((N_EDGES + 255) / 256);
  dim3 g_edge2((N_EDGES / 2 + 255) / 256);
  dim3 g_node((N_NODES * 64 + 255) / 256);
  dim3 g_nthr((N_NODES + 255) / 256);
  dim3 g_scan(NB_SCAN);

  // W fragment pack (bf16)
  pack_w_k<F_IN><<<dim3(16), blk, 0, stream>>>(W1l, W1r, Wb1);
  pack_w_k<H_DIM><<<dim3(4),  blk, 0, stream>>>(W2l, W2r, Wb2);
  // CSR build (multi-block scan)
  hist_k<<<g_edge, blk, 0, stream>>>(ei, cnt);
  scan1_k<<<g_scan, blk, 0, stream>>>(cnt, bsum);
  scan2_k<<<dim3(1), blk, 0, stream>>>(bsum, boff);
  scan3_k<<<g_scan, blk, 0, stream>>>(cnt, boff, rowptr, cursor);
  fill_k<<<g_edge, blk, 0, stream>>>(ei, cursor, esrc);
  expand_k<<<g_nthr, blk, 0, stream>>>(rowptr, edst);
  // Layer 1 (MFMA): m1 (bf16) -> uA, xr (fp32) -> fA
  gemm_mfma_k<F_IN, false><<<g_tile, blk, 0, stream>>>(x, Wb1, b1l, uA, fA);
  // h = relu(mean m1 + xr) -> uB (bf16)
  agg1_k<<<g_node, blk, 0, stream>>>(rowptr, esrc, uA, fA, uB);
  // Layer 2 (MFMA, bf16 input): m2 (bf16) -> uA, hr (fp32) -> fA
  gemm_mfma_k<H_DIM, true><<<g_tile, blk, 0, stream>>>(uB, Wb2, b2l, uA, fA);
  // z -> out (fp32) + zb -> uB (bf16)
  agg2_k<<<g_node, blk, 0, stream>>>(rowptr, esrc, uA, fA, out, uB);
  // Decode + loss (CSR order, bf16 gathers, 2 edges/thread)
  decode2_k<<<g_edge2, blk, 0, stream>>>(esrc, edst, uB, loss);
  fin_k<<<dim3(1), dim3(1), 0, stream>>>(loss, out);
}

// Round 13
// 329.378 us; speedup vs baseline: 3.2874x; 1.0310x over previous
//
#include <hip/hip_runtime.h>

// Problem constants (SVGA_7318624272625)
#define N_NODES 50000
#define N_EDGES 800000
#define F_IN    256
#define H_DIM   64
#define NB_SCAN ((N_NODES + 255) / 256)   // 196 scan blocks == dst buckets
#define TILE_A  8192                       // edges per binA block
#define MAXB    5632                       // max edges per bucket (avg 4081, sd 64)

typedef __attribute__((ext_vector_type(8))) short short8;
typedef __attribute__((ext_vector_type(4))) float floatx4;

__device__ __forceinline__ unsigned short f2bf(float f) {  // RNE fp32->bf16
  unsigned int u;
  __builtin_memcpy(&u, &f, 4);
  u += 0x7fffu + ((u >> 16) & 1u);
  return (unsigned short)(u >> 16);
}
__device__ __forceinline__ float bf2f(unsigned short s) {
  unsigned int v = ((unsigned int)s) << 16; float f; __builtin_memcpy(&f, &v, 4); return f;
}
__device__ __forceinline__ float bflo(unsigned int u) {
  unsigned int v = u << 16; float f; __builtin_memcpy(&f, &v, 4); return f;
}
__device__ __forceinline__ float bfhi(unsigned int u) {
  unsigned int v = u & 0xffff0000u; float f; __builtin_memcpy(&f, &v, 4); return f;
}

// Pack W[K,64] (fp32) -> bf16 MFMA B-fragments.
template<int K>
__global__ __launch_bounds__(256) void pack_w_k(
    const float* __restrict__ Wl, const float* __restrict__ Wr,
    unsigned short* __restrict__ Wb)
{
  int t = blockIdx.x * 256 + threadIdx.x;
  const int total = (K / 32) * 4 * 2 * 64;
  if (t >= total) return;
  int lane = t & 63;
  int f    = t >> 6;
  int m    = f & 1;
  int c    = (f >> 1) & 3;
  int ks   = f >> 3;
  const float* W = m ? Wr : Wl;
  int quad = lane >> 4, l15 = lane & 15;
  int col = c * 16 + l15;
  unsigned short u[8];
#pragma unroll
  for (int j = 0; j < 8; ++j) {
    int k = ks * 32 + quad * 8 + j;
    u[j] = f2bf(W[k * H_DIM + col]);
  }
  uint4 v;
  __builtin_memcpy(&v, u, 16);
  ((uint4*)Wb)[t] = v;
}

// MFMA dual-GEMM: outl = bf16(X@Wl + bl), outr = fp32(X@Wr).
template<int K, bool XBF16>
__global__ __launch_bounds__(256, 4) void gemm_mfma_k(
    const void* __restrict__ X_,
    const unsigned short* __restrict__ Wb,
    const float* __restrict__ bl,
    unsigned short* __restrict__ outl, float* __restrict__ outr)
{
  constexpr int KP = K + 8;                 // padded row length (bf16 units)
  __shared__ unsigned short xs[64 * KP];
  const int row0 = blockIdx.x * 64;
  if (XBF16) {
    const uint4* X = (const uint4*)X_;      // row = K bf16 = K/8 uint4
    const int CH = K / 8;
    for (int i = threadIdx.x; i < 64 * CH; i += 256) {
      int r = i / CH, c = i % CH;
      int row = row0 + r;
      uint4 v = (row < N_NODES) ? X[(size_t)row * CH + c] : make_uint4(0, 0, 0, 0);
      *(uint4*)&xs[r * KP + c * 8] = v;
    }
  } else {
    const float4* X = (const float4*)X_;
    const int CH = K / 4;
    for (int i = threadIdx.x; i < 64 * CH; i += 256) {
      int r = i / CH, c = i % CH;
      int row = row0 + r;
      float4 v = (row < N_NODES) ? X[(size_t)row * CH + c]
                                 : make_float4(0.f, 0.f, 0.f, 0.f);
      unsigned int lo = (unsigned int)f2bf(v.x) | ((unsigned int)f2bf(v.y) << 16);
      unsigned int hi = (unsigned int)f2bf(v.z) | ((unsigned int)f2bf(v.w) << 16);
      *(uint2*)&xs[r * KP + c * 4] = make_uint2(lo, hi);
    }
  }
  __syncthreads();

  const int lane = threadIdx.x & 63;
  const int w    = threadIdx.x >> 6;
  const int quad = lane >> 4;
  const int l15  = lane & 15;
  const int rloc = w * 16 + l15;            // A-frag row

  floatx4 accl[4], accr[4];
#pragma unroll
  for (int c = 0; c < 4; ++c) { accl[c] = (floatx4)0.f; accr[c] = (floatx4)0.f; }

  const uint4* wbase = (const uint4*)Wb;
#pragma unroll
  for (int ks = 0; ks < K / 32; ++ks) {
    short8 af = *(const short8*)&xs[rloc * KP + ks * 32 + quad * 8];
#pragma unroll
    for (int c = 0; c < 4; ++c) {
      uint4 rl = wbase[((ks * 4 + c) * 2 + 0) * 64 + lane];
      uint4 rr = wbase[((ks * 4 + c) * 2 + 1) * 64 + lane];
      short8 bfl, bfr;
      __builtin_memcpy(&bfl, &rl, 16);
      __builtin_memcpy(&bfr, &rr, 16);
      accl[c] = __builtin_amdgcn_mfma_f32_16x16x32_bf16(af, bfl, accl[c], 0, 0, 0);
      accr[c] = __builtin_amdgcn_mfma_f32_16x16x32_bf16(af, bfr, accr[c], 0, 0, 0);
    }
  }
#pragma unroll
  for (int c = 0; c < 4; ++c) {
    int col = c * 16 + l15;
    float bias = bl[col];
#pragma unroll
    for (int reg = 0; reg < 4; ++reg) {
      int row = row0 + w * 16 + quad * 4 + reg;
      if (row < N_NODES) {
        outl[(size_t)row * H_DIM + col] = f2bf(accl[c][reg] + bias);
        outr[(size_t)row * H_DIM + col] = accr[c][reg];
      }
    }
  }
}

// ---- CSR build ----
__global__ __launch_bounds__(256) void hist_k(const int* __restrict__ ei,
                                              int* __restrict__ cnt)
{
  int e = blockIdx.x * 256 + threadIdx.x;
  if (e >= N_EDGES) return;
  atomicAdd(&cnt[ei[N_EDGES + e]], 1);
}

__global__ __launch_bounds__(256) void scan1_k(const int* __restrict__ cnt,
                                               int* __restrict__ bsum)
{
  __shared__ int s[256];
  int idx = blockIdx.x * 256 + threadIdx.x;
  s[threadIdx.x] = (idx < N_NODES) ? cnt[idx] : 0;
  __syncthreads();
#pragma unroll
  for (int off = 128; off > 0; off >>= 1) {
    if (threadIdx.x < off) s[threadIdx.x] += s[threadIdx.x + off];
    __syncthreads();
  }
  if (threadIdx.x == 0) bsum[blockIdx.x] = s[0];
}

// scan2: bucket offsets boff (exclusive) + bucket cursor init for binA.
__global__ __launch_bounds__(256) void scan2_k(const int* __restrict__ bsum,
                                               int* __restrict__ boff,
                                               int* __restrict__ bcur)
{
  __shared__ int s[256];
  int t = threadIdx.x;
  int v = (t < NB_SCAN) ? bsum[t] : 0;
  s[t] = v;
  __syncthreads();
  for (int off = 1; off < 256; off <<= 1) {
    int u = (t >= off) ? s[t - off] : 0;
    __syncthreads();
    s[t] += u;
    __syncthreads();
  }
  if (t < NB_SCAN) { boff[t] = s[t] - v; bcur[t] = s[t] - v; }
}

__global__ __launch_bounds__(256) void scan3_k(const int* __restrict__ cnt,
                                               const int* __restrict__ boff,
                                               int* __restrict__ rowptr)
{
  __shared__ int s[256];
  int idx = blockIdx.x * 256 + threadIdx.x;
  int t = threadIdx.x;
  int v = (idx < N_NODES) ? cnt[idx] : 0;
  s[t] = v;
  __syncthreads();
  for (int off = 1; off < 256; off <<= 1) {
    int u = (t >= off) ? s[t - off] : 0;
    __syncthreads();
    s[t] += u;
    __syncthreads();
  }
  int excl = boff[blockIdx.x] + s[t] - v;
  if (idx < N_NODES) rowptr[idx] = excl;
  if (idx == N_NODES - 1) rowptr[N_NODES] = excl + v;   // == E
}

// binA: LDS-binned bucket scatter (replaces fill_k's 53MB partial-line writes).
// Each block bins TILE_A edges into 196 LDS lists, reserves global space with
// one atomic per (block,bucket), flushes wave-contiguous runs (~168B).
__global__ __launch_bounds__(256) void binA_k(const int* __restrict__ ei,
                                              int* __restrict__ bcur,
                                              unsigned int* __restrict__ ebuf)
{
  __shared__ int lcnt[256];
  __shared__ int lofs[256];
  __shared__ int lstart[256];
  __shared__ int gstart[256];
  __shared__ int lcur[256];
  __shared__ unsigned int ldata[TILE_A];   // 32 KB
  const int t = threadIdx.x;
  const int e0 = blockIdx.x * TILE_A;
  lcnt[t] = 0;
  __syncthreads();
  for (int i = t; i < TILE_A; i += 256) {
    int e = e0 + i;
    if (e < N_EDGES) atomicAdd(&lcnt[ei[N_EDGES + e] >> 8], 1);
  }
  __syncthreads();
  int v = lcnt[t];
  lofs[t] = v;
  __syncthreads();
  for (int off = 1; off < 256; off <<= 1) {
    int u = (t >= off) ? lofs[t - off] : 0;
    __syncthreads();
    lofs[t] += u;
    __syncthreads();
  }
  lstart[t] = lofs[t] - v;
  lcur[t]   = lofs[t] - v;
  if (t < NB_SCAN && v > 0) gstart[t] = atomicAdd(&bcur[t], v);
  __syncthreads();
  for (int i = t; i < TILE_A; i += 256) {
    int e = e0 + i;
    if (e < N_EDGES) {
      int s = ei[e], d = ei[N_EDGES + e];
      int p = atomicAdd(&lcur[d >> 8], 1);
      ldata[p] = ((unsigned int)s << 8) | (unsigned int)(d & 255);
    }
  }
  __syncthreads();
  int w = t >> 6, lane = t & 63;
  for (int b = w; b < NB_SCAN; b += 4) {
    int st = lstart[b], len = lcnt[b];
    if (len == 0) continue;
    int g = gstart[b];
    for (int j = lane; j < len; j += 64) ebuf[g + j] = ldata[st + j];
  }
}

// binB: per-bucket CSR finalize. Local 256-node hist+scan reproduces rowptr
// slots exactly (boff[b] + local exclusive scan == scan3's rowptr); final
// esrc write is fully coalesced.
__global__ __launch_bounds__(256) void binB_k(const unsigned int* __restrict__ ebuf,
                                              const int* __restrict__ boff,
                                              const int* __restrict__ bsum,
                                              int* __restrict__ esrc)
{
  __shared__ int ncnt[256];
  __shared__ int nscan[256];
  __shared__ int ncur[256];
  __shared__ unsigned int sdata[MAXB];     // 22 KB
  const int b = blockIdx.x, t = threadIdx.x;
  const int start = boff[b], len = bsum[b];
  ncnt[t] = 0;
  __syncthreads();
  for (int i = t; i < len; i += 256) atomicAdd(&ncnt[ebuf[start + i] & 255], 1);
  __syncthreads();
  int v = ncnt[t];
  nscan[t] = v;
  __syncthreads();
  for (int off = 1; off < 256; off <<= 1) {
    int u = (t >= off) ? nscan[t - off] : 0;
    __syncthreads();
    nscan[t] += u;
    __syncthreads();
  }
  ncur[t] = nscan[t] - v;
  __syncthreads();
  if (len <= MAXB) {
    for (int i = t; i < len; i += 256) {
      unsigned int e = ebuf[start + i];
      int p = atomicAdd(&ncur[e & 255], 1);
      sdata[p] = e >> 8;
    }
    __syncthreads();
    for (int i = t; i < len; i += 256) esrc[start + i] = (int)sdata[i];
  } else {  // statistically unreachable fallback (correct, uncoalesced)
    for (int i = t; i < len; i += 256) {
      unsigned int e = ebuf[start + i];
      int p = atomicAdd(&ncur[e & 255], 1);
      esrc[start + p] = (int)(e >> 8);
    }
  }
}

// expand rowptr -> edst: thread per node, sequential writes.
__global__ __launch_bounds__(256) void expand_k(const int* __restrict__ rowptr,
                                                int* __restrict__ edst)
{
  int n = blockIdx.x * 256 + threadIdx.x;
  if (n >= N_NODES) return;
  int b = rowptr[n], e = rowptr[n + 1];
  for (int i = b; i < e; ++i) edst[i] = n;
}

// ---- Fused aggregation: wave per dst node, lane = feature, bf16 messages ----
__device__ __forceinline__ float agg_row_b(const int* __restrict__ esrc,
                                           const unsigned short* __restrict__ m,
                                           int b, int e, int lane)
{
  float a0 = 0.f, a1 = 0.f, a2 = 0.f, a3 = 0.f;
  int i = b;
  for (; i + 4 <= e; i += 4) {
    int s0 = esrc[i], s1 = esrc[i + 1], s2 = esrc[i + 2], s3 = esrc[i + 3];
    a0 += bf2f(m[(size_t)s0 * H_DIM + lane]);
    a1 += bf2f(m[(size_t)s1 * H_DIM + lane]);
    a2 += bf2f(m[(size_t)s2 * H_DIM + lane]);
    a3 += bf2f(m[(size_t)s3 * H_DIM + lane]);
  }
  for (; i < e; ++i) a0 += bf2f(m[(size_t)esrc[i] * H_DIM + lane]);
  return (a0 + a1) + (a2 + a3);
}

// h = relu(mean m1 + xr) -> bf16
__global__ __launch_bounds__(256) void agg1_k(
    const int* __restrict__ rowptr, const int* __restrict__ esrc,
    const unsigned short* __restrict__ m, const float* __restrict__ xr,
    unsigned short* __restrict__ h)
{
  int gid = blockIdx.x * 256 + threadIdx.x;
  int row = gid >> 6, lane = gid & 63;
  if (row >= N_NODES) return;
  int b = rowptr[row], e = rowptr[row + 1];
  float acc = agg_row_b(esrc, m, b, e, lane);
  float dv = fmaxf((float)(e - b), 1.f);
  size_t o = (size_t)row * H_DIM + lane;
  h[o] = f2bf(fmaxf(acc / dv + xr[o], 0.f));
}

// z = unitnorm(mean m2 + hr) -> fp32 d_out + bf16 copy (decode gathers)
__global__ __launch_bounds__(256) void agg2_k(
    const int* __restrict__ rowptr, const int* __restrict__ esrc,
    const unsigned short* __restrict__ m, const float* __restrict__ hr,
    float* __restrict__ zout, unsigned short* __restrict__ zb)
{
  int gid = blockIdx.x * 256 + threadIdx.x;
  int row = gid >> 6, lane = gid & 63;
  if (row >= N_NODES) return;
  int b = rowptr[row], e = rowptr[row + 1];
  float acc = agg_row_b(esrc, m, b, e, lane);
  float dv = fmaxf((float)(e - b), 1.f);
  size_t o = (size_t)row * H_DIM + lane;
  float v = acc / dv + hr[o];
  float ss = v * v;
#pragma unroll
  for (int mm = 32; mm >= 1; mm >>= 1) ss += __shfl_xor(ss, mm, 64);
  float z = v * rsqrtf(fmaxf(ss, 1e-30f));
  zout[o] = z;
  zb[o] = f2bf(z);
}

// Decode: two edges per thread, CSR order, bf16 z rows.
__global__ __launch_bounds__(256) void decode2_k(
    const int* __restrict__ esrc, const int* __restrict__ edst,
    const unsigned short* __restrict__ zb, float* __restrict__ loss)
{
  int i0 = (blockIdx.x * 256 + threadIdx.x) * 2;
  float part = 0.f;
  if (i0 + 1 < N_EDGES) {
    int s0 = esrc[i0],     d0 = edst[i0];
    int s1 = esrc[i0 + 1], d1 = edst[i0 + 1];
    const uint4* zs0 = (const uint4*)(zb + (size_t)s0 * H_DIM);
    const uint4* zd0 = (const uint4*)(zb + (size_t)d0 * H_DIM);
    const uint4* zs1 = (const uint4*)(zb + (size_t)s1 * H_DIM);
    const uint4* zd1 = (const uint4*)(zb + (size_t)d1 * H_DIM);
    float p0 = 0.f, p1 = 0.f;
#pragma unroll 4
    for (int k = 0; k < 8; ++k) {          // 8 uint4 = 64 bf16 = full row
      uint4 a0 = zs0[k], b0 = zd0[k], a1 = zs1[k], b1 = zd1[k];
      unsigned int au0[4] = {a0.x, a0.y, a0.z, a0.w};
      unsigned int bu0[4] = {b0.x, b0.y, b0.z, b0.w};
      unsigned int au1[4] = {a1.x, a1.y, a1.z, a1.w};
      unsigned int bu1[4] = {b1.x, b1.y, b1.z, b1.w};
#pragma unroll
      for (int j = 0; j < 4; ++j) {
        p0 = fmaf(bflo(au0[j]), bflo(bu0[j]), p0);
        p0 = fmaf(bfhi(au0[j]), bfhi(bu0[j]), p0);
        p1 = fmaf(bflo(au1[j]), bflo(bu1[j]), p1);
        p1 = fmaf(bfhi(au1[j]), bfhi(bu1[j]), p1);
      }
    }
    part  = fmaxf(-p0, 0.f) + log1pf(expf(-fabsf(p0)));
    part += fmaxf(-p1, 0.f) + log1pf(expf(-fabsf(p1)));
  }
#pragma unroll
  for (int m = 32; m >= 1; m >>= 1) part += __shfl_xor(part, m, 64);
  __shared__ float sbuf[4];
  int lane = threadIdx.x & 63, w = threadIdx.x >> 6;
  if (lane == 0) sbuf[w] = part;
  __syncthreads();
  if (threadIdx.x == 0)
    atomicAdd(loss, sbuf[0] + sbuf[1] + sbuf[2] + sbuf[3]);
}

__global__ void fin_k(const float* __restrict__ loss, float* __restrict__ out)
{
  out[(size_t)N_NODES * H_DIM] = loss[0] / (float)N_EDGES;
}

extern "C" void kernel_launch(void* const* d_in, const int* in_sizes, int n_in,
                              void* d_out, int out_size, void* d_ws, size_t ws_size,
                              hipStream_t stream)
{
  (void)in_sizes; (void)n_in; (void)out_size; (void)ws_size;
  const float* x   = (const float*)d_in[0];
  const int*   ei  = (const int*)d_in[1];
  const float* W1l = (const float*)d_in[2];
  const float* b1l = (const float*)d_in[3];
  const float* W1r = (const float*)d_in[4];
  const float* W2l = (const float*)d_in[5];
  const float* b2l = (const float*)d_in[6];
  const float* W2r = (const float*)d_in[7];
  float* out = (float*)d_out;  // fp32: z [N*H] ++ loss [1]

  const size_t NH = (size_t)N_NODES * H_DIM;
  // uA = m1 then m2 (bf16); fA = xr then hr (fp32); uB = h then zb (bf16).
  unsigned short* uA = (unsigned short*)d_ws;   // NH ushort
  unsigned short* uB = uA + NH;                 // NH ushort
  float* fA     = (float*)(uB + NH);            // NH float
  float* loss   = fA + NH;
  int*   cnt    = (int*)(loss + 1);
  int*   rowptr = cnt + N_NODES;         // N+1
  int*   esrc   = rowptr + N_NODES + 1;  // E
  int*   edst   = esrc + N_EDGES;        // E
  unsigned int* ebuf = (unsigned int*)(edst + N_EDGES);  // E (bucket-binned)
  int*   bsum   = (int*)(ebuf + N_EDGES);  // NB_SCAN
  int*   boff   = bsum + NB_SCAN;          // NB_SCAN
  int*   bcur   = boff + NB_SCAN;          // NB_SCAN
  unsigned short* Wb1 = (unsigned short*)(bcur + NB_SCAN);   // 64 KB
  unsigned short* Wb2 = Wb1 + (F_IN / 32) * 4 * 2 * 64 * 8;  // 16 KB

  hipMemsetAsync(cnt,  0, sizeof(int) * N_NODES, stream);
  hipMemsetAsync(loss, 0, sizeof(float), stream);

  dim3 blk(256);
  dim3 g_tile((N_NODES + 63) / 64);
  dim3 g_edge((N_EDGES + 255) / 256);
  dim3 g_edge2((N_EDGES / 2 + 255) / 256);
  dim3 g_node((N_NODES * 64 + 255) / 256);
  dim3 g_nthr((N_NODES + 255) / 256);
  dim3 g_scan(NB_SCAN);
  dim3 g_binA((N_EDGES + TILE_A - 1) / TILE_A);   // 98

  // W fragment pack (bf16)
  pack_w_k<F_IN><<<dim3(16), blk, 0, stream>>>(W1l, W1r, Wb1);
  pack_w_k<H_DIM><<<dim3(4),  blk, 0, stream>>>(W2l, W2r, Wb2);
  // CSR build: hist -> scans -> LDS-binned bucket scatter -> bucket CSR
  hist_k<<<g_edge, blk, 0, stream>>>(ei, cnt);
  scan1_k<<<g_scan, blk, 0, stream>>>(cnt, bsum);
  scan2_k<<<dim3(1), blk, 0, stream>>>(bsum, boff, bcur);
  scan3_k<<<g_scan, blk, 0, stream>>>(cnt, boff, rowptr);
  binA_k<<<g_binA, blk, 0, stream>>>(ei, bcur, ebuf);
  binB_k<<<g_scan, blk, 0, stream>>>(ebuf, boff, bsum, esrc);
  expand_k<<<g_nthr, blk, 0, stream>>>(rowptr, edst);
  // Layer 1 (MFMA): m1 (bf16) -> uA, xr (fp32) -> fA
  gemm_mfma_k<F_IN, false><<<g_tile, blk, 0, stream>>>(x, Wb1, b1l, uA, fA);
  agg1_k<<<g_node, blk, 0, stream>>>(rowptr, esrc, uA, fA, uB);
  // Layer 2 (MFMA, bf16 input): m2 (bf16) -> uA, hr (fp32) -> fA
  gemm_mfma_k<H_DIM, true><<<g_tile, blk, 0, stream>>>(uB, Wb2, b2l, uA, fA);
  agg2_k<<<g_node, blk, 0, stream>>>(rowptr, esrc, uA, fA, out, uB);
  // Decode + loss (CSR order, bf16 gathers, 2 edges/thread)
  decode2_k<<<g_edge2, blk, 0, stream>>>(esrc, edst, uB, loss);
  fin_k<<<dim3(1), dim3(1), 0, stream>>>(loss, out);
}

// Round 14
// 308.528 us; speedup vs baseline: 3.5096x; 1.0676x over previous
//
#include <hip/hip_runtime.h>

// Problem constants (SVGA_7318624272625)
#define N_NODES 50000
#define N_EDGES 800000
#define F_IN    256
#define H_DIM   64
#define NB_SCAN ((N_NODES + 255) / 256)   // 196 scan blocks == dst buckets
#define TILE_A  8192                       // edges per binA block
#define MAXB    5632                       // max edges per bucket (avg 4081)

typedef __attribute__((ext_vector_type(8))) short short8;
typedef __attribute__((ext_vector_type(4))) float floatx4;

__device__ __forceinline__ unsigned short f2bf(float f) {  // RNE fp32->bf16
  unsigned int u;
  __builtin_memcpy(&u, &f, 4);
  u += 0x7fffu + ((u >> 16) & 1u);
  return (unsigned short)(u >> 16);
}
__device__ __forceinline__ float bf2f(unsigned short s) {
  unsigned int v = ((unsigned int)s) << 16; float f; __builtin_memcpy(&f, &v, 4); return f;
}
__device__ __forceinline__ float bflo(unsigned int u) {
  unsigned int v = u << 16; float f; __builtin_memcpy(&f, &v, 4); return f;
}
__device__ __forceinline__ float bfhi(unsigned int u) {
  unsigned int v = u & 0xffff0000u; float f; __builtin_memcpy(&f, &v, 4); return f;
}

// Pack helper: W[K,64] (fp32) -> bf16 MFMA B-fragments, frag id
// f = (ks*4+c)*2+m ; lane L, j holds B[k=ks*32+(L>>4)*8+j][n=c*16+(L&15)].
template<int K>
__device__ __forceinline__ void pack_body(int t, const float* __restrict__ Wl,
                                          const float* __restrict__ Wr,
                                          unsigned short* __restrict__ Wb)
{
  int lane = t & 63;
  int f    = t >> 6;
  int m    = f & 1;
  int c    = (f >> 1) & 3;
  int ks   = f >> 3;
  const float* W = m ? Wr : Wl;
  int quad = lane >> 4, l15 = lane & 15;
  int col = c * 16 + l15;
  unsigned short u[8];
#pragma unroll
  for (int j = 0; j < 8; ++j) {
    int k = ks * 32 + quad * 8 + j;
    u[j] = f2bf(W[k * H_DIM + col]);
  }
  uint4 v;
  __builtin_memcpy(&v, u, 16);
  ((uint4*)Wb)[t] = v;
}

// Fused pack: blocks 0-15 pack W1 (4096 frags*lanes), 16-19 pack W2 (1024);
// also zeroes the loss accumulator slot (d_out is poisoned 0xAA pre-call).
__global__ __launch_bounds__(256) void pack_all_k(
    const float* __restrict__ W1l, const float* __restrict__ W1r,
    const float* __restrict__ W2l, const float* __restrict__ W2r,
    unsigned short* __restrict__ Wb1, unsigned short* __restrict__ Wb2,
    float* __restrict__ loss_slot)
{
  if (blockIdx.x == 0 && threadIdx.x == 0) loss_slot[0] = 0.f;
  int b = blockIdx.x;
  if (b < 16) {
    pack_body<F_IN>(b * 256 + threadIdx.x, W1l, W1r, Wb1);
  } else {
    pack_body<H_DIM>((b - 16) * 256 + threadIdx.x, W2l, W2r, Wb2);
  }
}

// MFMA dual-GEMM: outl = bf16(X@Wl + bl), outr = bf16(X@Wr).
template<int K, bool XBF16>
__global__ __launch_bounds__(256, 4) void gemm_mfma_k(
    const void* __restrict__ X_,
    const unsigned short* __restrict__ Wb,
    const float* __restrict__ bl,
    unsigned short* __restrict__ outl, unsigned short* __restrict__ outr)
{
  constexpr int KP = K + 8;                 // padded row length (bf16 units)
  __shared__ unsigned short xs[64 * KP];
  const int row0 = blockIdx.x * 64;
  if (XBF16) {
    const uint4* X = (const uint4*)X_;      // row = K bf16 = K/8 uint4
    const int CH = K / 8;
    for (int i = threadIdx.x; i < 64 * CH; i += 256) {
      int r = i / CH, c = i % CH;
      int row = row0 + r;
      uint4 v = (row < N_NODES) ? X[(size_t)row * CH + c] : make_uint4(0, 0, 0, 0);
      *(uint4*)&xs[r * KP + c * 8] = v;
    }
  } else {
    const float4* X = (const float4*)X_;
    const int CH = K / 4;
    for (int i = threadIdx.x; i < 64 * CH; i += 256) {
      int r = i / CH, c = i % CH;
      int row = row0 + r;
      float4 v = (row < N_NODES) ? X[(size_t)row * CH + c]
                                 : make_float4(0.f, 0.f, 0.f, 0.f);
      unsigned int lo = (unsigned int)f2bf(v.x) | ((unsigned int)f2bf(v.y) << 16);
      unsigned int hi = (unsigned int)f2bf(v.z) | ((unsigned int)f2bf(v.w) << 16);
      *(uint2*)&xs[r * KP + c * 4] = make_uint2(lo, hi);
    }
  }
  __syncthreads();

  const int lane = threadIdx.x & 63;
  const int w    = threadIdx.x >> 6;
  const int quad = lane >> 4;
  const int l15  = lane & 15;
  const int rloc = w * 16 + l15;            // A-frag row

  floatx4 accl[4], accr[4];
#pragma unroll
  for (int c = 0; c < 4; ++c) { accl[c] = (floatx4)0.f; accr[c] = (floatx4)0.f; }

  const uint4* wbase = (const uint4*)Wb;
#pragma unroll
  for (int ks = 0; ks < K / 32; ++ks) {
    short8 af = *(const short8*)&xs[rloc * KP + ks * 32 + quad * 8];
#pragma unroll
    for (int c = 0; c < 4; ++c) {
      uint4 rl = wbase[((ks * 4 + c) * 2 + 0) * 64 + lane];
      uint4 rr = wbase[((ks * 4 + c) * 2 + 1) * 64 + lane];
      short8 bfl, bfr;
      __builtin_memcpy(&bfl, &rl, 16);
      __builtin_memcpy(&bfr, &rr, 16);
      accl[c] = __builtin_amdgcn_mfma_f32_16x16x32_bf16(af, bfl, accl[c], 0, 0, 0);
      accr[c] = __builtin_amdgcn_mfma_f32_16x16x32_bf16(af, bfr, accr[c], 0, 0, 0);
    }
  }
#pragma unroll
  for (int c = 0; c < 4; ++c) {
    int col = c * 16 + l15;
    float bias = bl[col];
#pragma unroll
    for (int reg = 0; reg < 4; ++reg) {
      int row = row0 + w * 16 + quad * 4 + reg;
      if (row < N_NODES) {
        outl[(size_t)row * H_DIM + col] = f2bf(accl[c][reg] + bias);
        outr[(size_t)row * H_DIM + col] = f2bf(accr[c][reg]);
      }
    }
  }
}

// ---- CSR build ----
__global__ __launch_bounds__(256) void hist_k(const int* __restrict__ ei,
                                              int* __restrict__ cnt)
{
  int e = blockIdx.x * 256 + threadIdx.x;
  if (e >= N_EDGES) return;
  atomicAdd(&cnt[ei[N_EDGES + e]], 1);
}

__global__ __launch_bounds__(256) void scan1_k(const int* __restrict__ cnt,
                                               int* __restrict__ bsum)
{
  __shared__ int s[256];
  int idx = blockIdx.x * 256 + threadIdx.x;
  s[threadIdx.x] = (idx < N_NODES) ? cnt[idx] : 0;
  __syncthreads();
#pragma unroll
  for (int off = 128; off > 0; off >>= 1) {
    if (threadIdx.x < off) s[threadIdx.x] += s[threadIdx.x + off];
    __syncthreads();
  }
  if (threadIdx.x == 0) bsum[blockIdx.x] = s[0];
}

// scan2: bucket offsets boff (exclusive) + bucket cursor init for binA.
__global__ __launch_bounds__(256) void scan2_k(const int* __restrict__ bsum,
                                               int* __restrict__ boff,
                                               int* __restrict__ bcur)
{
  __shared__ int s[256];
  int t = threadIdx.x;
  int v = (t < NB_SCAN) ? bsum[t] : 0;
  s[t] = v;
  __syncthreads();
  for (int off = 1; off < 256; off <<= 1) {
    int u = (t >= off) ? s[t - off] : 0;
    __syncthreads();
    s[t] += u;
    __syncthreads();
  }
  if (t < NB_SCAN) { boff[t] = s[t] - v; bcur[t] = s[t] - v; }
}

__global__ __launch_bounds__(256) void scan3_k(const int* __restrict__ cnt,
                                               const int* __restrict__ boff,
                                               int* __restrict__ rowptr)
{
  __shared__ int s[256];
  int idx = blockIdx.x * 256 + threadIdx.x;
  int t = threadIdx.x;
  int v = (idx < N_NODES) ? cnt[idx] : 0;
  s[t] = v;
  __syncthreads();
  for (int off = 1; off < 256; off <<= 1) {
    int u = (t >= off) ? s[t - off] : 0;
    __syncthreads();
    s[t] += u;
    __syncthreads();
  }
  int excl = boff[blockIdx.x] + s[t] - v;
  if (idx < N_NODES) rowptr[idx] = excl;
  if (idx == N_NODES - 1) rowptr[N_NODES] = excl + v;   // == E
}

// binA: LDS-binned bucket scatter; one global atomic per (block,bucket),
// wave-contiguous flush runs.
__global__ __launch_bounds__(256) void binA_k(const int* __restrict__ ei,
                                              int* __restrict__ bcur,
                                              unsigned int* __restrict__ ebuf)
{
  __shared__ int lcnt[256];
  __shared__ int lofs[256];
  __shared__ int lstart[256];
  __shared__ int gstart[256];
  __shared__ int lcur[256];
  __shared__ unsigned int ldata[TILE_A];   // 32 KB
  const int t = threadIdx.x;
  const int e0 = blockIdx.x * TILE_A;
  lcnt[t] = 0;
  __syncthreads();
  for (int i = t; i < TILE_A; i += 256) {
    int e = e0 + i;
    if (e < N_EDGES) atomicAdd(&lcnt[ei[N_EDGES + e] >> 8], 1);
  }
  __syncthreads();
  int v = lcnt[t];
  lofs[t] = v;
  __syncthreads();
  for (int off = 1; off < 256; off <<= 1) {
    int u = (t >= off) ? lofs[t - off] : 0;
    __syncthreads();
    lofs[t] += u;
    __syncthreads();
  }
  lstart[t] = lofs[t] - v;
  lcur[t]   = lofs[t] - v;
  if (t < NB_SCAN && v > 0) gstart[t] = atomicAdd(&bcur[t], v);
  __syncthreads();
  for (int i = t; i < TILE_A; i += 256) {
    int e = e0 + i;
    if (e < N_EDGES) {
      int s = ei[e], d = ei[N_EDGES + e];
      int p = atomicAdd(&lcur[d >> 8], 1);
      ldata[p] = ((unsigned int)s << 8) | (unsigned int)(d & 255);
    }
  }
  __syncthreads();
  int w = t >> 6, lane = t & 63;
  for (int b = w; b < NB_SCAN; b += 4) {
    int st = lstart[b], len = lcnt[b];
    if (len == 0) continue;
    int g = gstart[b];
    for (int j = lane; j < len; j += 64) ebuf[g + j] = ldata[st + j];
  }
}

// binB: per-bucket CSR finalize + edst expand (fused R14).  Local hist+scan
// reproduces rowptr slots (boff[b] + local exclusive scan); esrc write
// coalesced; edst written as per-node contiguous runs.
__global__ __launch_bounds__(256) void binB_k(const unsigned int* __restrict__ ebuf,
                                              const int* __restrict__ boff,
                                              const int* __restrict__ bsum,
                                              int* __restrict__ esrc,
                                              int* __restrict__ edst)
{
  __shared__ int ncnt[256];
  __shared__ int nscan[256];
  __shared__ int ncur[256];
  __shared__ unsigned int sdata[MAXB];     // 22 KB
  const int b = blockIdx.x, t = threadIdx.x;
  const int start = boff[b], len = bsum[b];
  ncnt[t] = 0;
  __syncthreads();
  for (int i = t; i < len; i += 256) atomicAdd(&ncnt[ebuf[start + i] & 255], 1);
  __syncthreads();
  int v = ncnt[t];
  nscan[t] = v;
  __syncthreads();
  for (int off = 1; off < 256; off <<= 1) {
    int u = (t >= off) ? nscan[t - off] : 0;
    __syncthreads();
    nscan[t] += u;
    __syncthreads();
  }
  ncur[t] = nscan[t] - v;
  __syncthreads();
  if (len <= MAXB) {
    for (int i = t; i < len; i += 256) {
      unsigned int e = ebuf[start + i];
      int p = atomicAdd(&ncur[e & 255], 1);
      sdata[p] = e >> 8;
    }
    __syncthreads();
    for (int i = t; i < len; i += 256) esrc[start + i] = (int)sdata[i];
  } else {  // statistically unreachable fallback
    for (int i = t; i < len; i += 256) {
      unsigned int e = ebuf[start + i];
      int p = atomicAdd(&ncur[e & 255], 1);
      esrc[start + p] = (int)(e >> 8);
    }
  }
  // edst expand: node (b*256+t) owns slots [start+nscan[t]-v, start+nscan[t])
  int node = b * 256 + t;
  int s0 = start + nscan[t] - v;
  for (int j = 0; j < v; ++j) edst[s0 + j] = node;
}

// ---- Fused aggregation: wave per dst node, lane = feature, bf16 everywhere ----
__device__ __forceinline__ float agg_row_b(const int* __restrict__ esrc,
                                           const unsigned short* __restrict__ m,
                                           int b, int e, int lane)
{
  float a0 = 0.f, a1 = 0.f, a2 = 0.f, a3 = 0.f;
  float a4 = 0.f, a5 = 0.f, a6 = 0.f, a7 = 0.f;
  int i = b;
  for (; i + 8 <= e; i += 8) {
    int s0 = esrc[i],     s1 = esrc[i + 1], s2 = esrc[i + 2], s3 = esrc[i + 3];
    int s4 = esrc[i + 4], s5 = esrc[i + 5], s6 = esrc[i + 6], s7 = esrc[i + 7];
    a0 += bf2f(m[(size_t)s0 * H_DIM + lane]);
    a1 += bf2f(m[(size_t)s1 * H_DIM + lane]);
    a2 += bf2f(m[(size_t)s2 * H_DIM + lane]);
    a3 += bf2f(m[(size_t)s3 * H_DIM + lane]);
    a4 += bf2f(m[(size_t)s4 * H_DIM + lane]);
    a5 += bf2f(m[(size_t)s5 * H_DIM + lane]);
    a6 += bf2f(m[(size_t)s6 * H_DIM + lane]);
    a7 += bf2f(m[(size_t)s7 * H_DIM + lane]);
  }
  for (; i + 4 <= e; i += 4) {
    int s0 = esrc[i], s1 = esrc[i + 1], s2 = esrc[i + 2], s3 = esrc[i + 3];
    a0 += bf2f(m[(size_t)s0 * H_DIM + lane]);
    a1 += bf2f(m[(size_t)s1 * H_DIM + lane]);
    a2 += bf2f(m[(size_t)s2 * H_DIM + lane]);
    a3 += bf2f(m[(size_t)s3 * H_DIM + lane]);
  }
  for (; i < e; ++i) a0 += bf2f(m[(size_t)esrc[i] * H_DIM + lane]);
  return ((a0 + a1) + (a2 + a3)) + ((a4 + a5) + (a6 + a7));
}

// h = relu(mean m1 + xr) -> bf16
__global__ __launch_bounds__(256) void agg1_k(
    const int* __restrict__ rowptr, const int* __restrict__ esrc,
    const unsigned short* __restrict__ m, const unsigned short* __restrict__ xr,
    unsigned short* __restrict__ h)
{
  int gid = blockIdx.x * 256 + threadIdx.x;
  int row = gid >> 6, lane = gid & 63;
  if (row >= N_NODES) return;
  int b = rowptr[row], e = rowptr[row + 1];
  float acc = agg_row_b(esrc, m, b, e, lane);
  float dv = fmaxf((float)(e - b), 1.f);
  size_t o = (size_t)row * H_DIM + lane;
  h[o] = f2bf(fmaxf(acc / dv + bf2f(xr[o]), 0.f));
}

// z = unitnorm(mean m2 + hr) -> fp32 d_out + bf16 copy (decode gathers)
__global__ __launch_bounds__(256) void agg2_k(
    const int* __restrict__ rowptr, const int* __restrict__ esrc,
    const unsigned short* __restrict__ m, const unsigned short* __restrict__ hr,
    float* __restrict__ zout, unsigned short* __restrict__ zb)
{
  int gid = blockIdx.x * 256 + threadIdx.x;
  int row = gid >> 6, lane = gid & 63;
  if (row >= N_NODES) return;
  int b = rowptr[row], e = rowptr[row + 1];
  float acc = agg_row_b(esrc, m, b, e, lane);
  float dv = fmaxf((float)(e - b), 1.f);
  size_t o = (size_t)row * H_DIM + lane;
  float v = acc / dv + bf2f(hr[o]);
  float ss = v * v;
#pragma unroll
  for (int mm = 32; mm >= 1; mm >>= 1) ss += __shfl_xor(ss, mm, 64);
  float z = v * rsqrtf(fmaxf(ss, 1e-30f));
  zout[o] = z;
  zb[o] = f2bf(z);
}

// Decode: two edges per thread, CSR order, bf16 z rows; adds part/E directly
// into out[N*H] (zeroed by pack_all_k) -- fin_k eliminated.
__global__ __launch_bounds__(256) void decode2_k(
    const int* __restrict__ esrc, const int* __restrict__ edst,
    const unsigned short* __restrict__ zb, float* __restrict__ loss_slot)
{
  int i0 = (blockIdx.x * 256 + threadIdx.x) * 2;
  float part = 0.f;
  if (i0 + 1 < N_EDGES) {
    int s0 = esrc[i0],     d0 = edst[i0];
    int s1 = esrc[i0 + 1], d1 = edst[i0 + 1];
    const uint4* zs0 = (const uint4*)(zb + (size_t)s0 * H_DIM);
    const uint4* zd0 = (const uint4*)(zb + (size_t)d0 * H_DIM);
    const uint4* zs1 = (const uint4*)(zb + (size_t)s1 * H_DIM);
    const uint4* zd1 = (const uint4*)(zb + (size_t)d1 * H_DIM);
    float p0 = 0.f, p1 = 0.f;
#pragma unroll 4
    for (int k = 0; k < 8; ++k) {          // 8 uint4 = 64 bf16 = full row
      uint4 a0 = zs0[k], b0 = zd0[k], a1 = zs1[k], b1 = zd1[k];
      unsigned int au0[4] = {a0.x, a0.y, a0.z, a0.w};
      unsigned int bu0[4] = {b0.x, b0.y, b0.z, b0.w};
      unsigned int au1[4] = {a1.x, a1.y, a1.z, a1.w};
      unsigned int bu1[4] = {b1.x, b1.y, b1.z, b1.w};
#pragma unroll
      for (int j = 0; j < 4; ++j) {
        p0 = fmaf(bflo(au0[j]), bflo(bu0[j]), p0);
        p0 = fmaf(bfhi(au0[j]), bfhi(bu0[j]), p0);
        p1 = fmaf(bflo(au1[j]), bflo(bu1[j]), p1);
        p1 = fmaf(bfhi(au1[j]), bfhi(bu1[j]), p1);
      }
    }
    part  = fmaxf(-p0, 0.f) + log1pf(expf(-fabsf(p0)));
    part += fmaxf(-p1, 0.f) + log1pf(expf(-fabsf(p1)));
  }
#pragma unroll
  for (int m = 32; m >= 1; m >>= 1) part += __shfl_xor(part, m, 64);
  __shared__ float sbuf[4];
  int lane = threadIdx.x & 63, w = threadIdx.x >> 6;
  if (lane == 0) sbuf[w] = part;
  __syncthreads();
  if (threadIdx.x == 0)
    atomicAdd(loss_slot, (sbuf[0] + sbuf[1] + sbuf[2] + sbuf[3]) * (1.0f / N_EDGES));
}

extern "C" void kernel_launch(void* const* d_in, const int* in_sizes, int n_in,
                              void* d_out, int out_size, void* d_ws, size_t ws_size,
                              hipStream_t stream)
{
  (void)in_sizes; (void)n_in; (void)out_size; (void)ws_size;
  const float* x   = (const float*)d_in[0];
  const int*   ei  = (const int*)d_in[1];
  const float* W1l = (const float*)d_in[2];
  const float* b1l = (const float*)d_in[3];
  const float* W1r = (const float*)d_in[4];
  const float* W2l = (const float*)d_in[5];
  const float* b2l = (const float*)d_in[6];
  const float* W2r = (const float*)d_in[7];
  float* out = (float*)d_out;  // fp32: z [N*H] ++ loss [1]
  float* loss_slot = out + (size_t)N_NODES * H_DIM;

  const size_t NH = (size_t)N_NODES * H_DIM;
  // uA = m1 then m2; uB = h then zb; uC = xr then hr (all bf16).
  unsigned short* uA = (unsigned short*)d_ws;   // NH ushort
  unsigned short* uB = uA + NH;                 // NH ushort
  unsigned short* uC = uB + NH;                 // NH ushort
  int*   cnt    = (int*)(uC + NH);
  int*   rowptr = cnt + N_NODES;         // N+1
  int*   esrc   = rowptr + N_NODES + 1;  // E
  int*   edst   = esrc + N_EDGES;        // E
  unsigned int* ebuf = (unsigned int*)(edst + N_EDGES);  // E (bucket-binned)
  int*   bsum   = (int*)(ebuf + N_EDGES);  // NB_SCAN
  int*   boff   = bsum + NB_SCAN;          // NB_SCAN
  int*   bcur   = boff + NB_SCAN;          // NB_SCAN
  unsigned short* Wb1 = (unsigned short*)(bcur + NB_SCAN);   // 64 KB
  unsigned short* Wb2 = Wb1 + (F_IN / 32) * 4 * 2 * 64 * 8;  // 16 KB

  hipMemsetAsync(cnt, 0, sizeof(int) * N_NODES, stream);

  dim3 blk(256);
  dim3 g_tile((N_NODES + 63) / 64);
  dim3 g_edge((N_EDGES + 255) / 256);
  dim3 g_edge2((N_EDGES / 2 + 255) / 256);
  dim3 g_node((N_NODES * 64 + 255) / 256);
  dim3 g_scan(NB_SCAN);
  dim3 g_binA((N_EDGES + TILE_A - 1) / TILE_A);   // 98

  // Pack W1+W2 fragments (bf16) + zero loss slot
  pack_all_k<<<dim3(20), blk, 0, stream>>>(W1l, W1r, W2l, W2r, Wb1, Wb2, loss_slot);
  // CSR build: hist -> scans -> LDS-binned bucket scatter -> bucket CSR+edst
  hist_k<<<g_edge, blk, 0, stream>>>(ei, cnt);
  scan1_k<<<g_scan, blk, 0, stream>>>(cnt, bsum);
  scan2_k<<<dim3(1), blk, 0, stream>>>(bsum, boff, bcur);
  scan3_k<<<g_scan, blk, 0, stream>>>(cnt, boff, rowptr);
  binA_k<<<g_binA, blk, 0, stream>>>(ei, bcur, ebuf);
  binB_k<<<g_scan, blk, 0, stream>>>(ebuf, boff, bsum, esrc, edst);
  // Layer 1 (MFMA): m1 -> uA, xr -> uC (bf16)
  gemm_mfma_k<F_IN, false><<<g_tile, blk, 0, stream>>>(x, Wb1, b1l, uA, uC);
  agg1_k<<<g_node, blk, 0, stream>>>(rowptr, esrc, uA, uC, uB);
  // Layer 2 (MFMA, bf16 input): m2 -> uA, hr -> uC (bf16)
  gemm_mfma_k<H_DIM, true><<<g_tile, blk, 0, stream>>>(uB, Wb2, b2l, uA, uC);
  agg2_k<<<g_node, blk, 0, stream>>>(rowptr, esrc, uA, uC, out, uB);
  // Decode + loss (CSR order, bf16 gathers, 2 edges/thread)
  decode2_k<<<g_edge2, blk, 0, stream>>>(esrc, edst, uB, loss_slot);
}